// Round 12
// baseline (2163.173 us; speedup 1.0000x reference)
//
#include <hip/hip_runtime.h>
#include <stdint.h>

// ---------------- problem constants ----------------
#define BATCH 8
#define NTOK 4096          // 64*64
#define CDIM 512
#define TTXT 77
#define TPAD 80
#define NHEAD 8
#define HDIM 64
#define HID 2048           // 4*C
#define MROWS 32768        // B*NTOK
#define NEGINF (-1e30f)

typedef __attribute__((ext_vector_type(8))) short short8;
typedef __attribute__((ext_vector_type(4))) float f32x4;

__device__ __forceinline__ float b2f(unsigned short u) {
    union { unsigned int i; float f; } x; x.i = ((unsigned int)u) << 16; return x.f;
}
__device__ __forceinline__ unsigned short f2b(float f) {
    union { float f; unsigned int i; } x; x.f = f;
    unsigned int i = x.i;
    return (unsigned short)((i + 0x7fffu + ((i >> 16) & 1u)) >> 16);
}

// async global->LDS, 16B per lane; LDS dest must be linear in lane order
__device__ __forceinline__ void gload16(const void* g, void* l) {
    __builtin_amdgcn_global_load_lds(
        (const __attribute__((address_space(1))) unsigned int*)g,
        (__attribute__((address_space(3))) unsigned int*)l, 16, 0, 0);
}

// ---------------- workspace layout (bytes) ----------------
#define OFF_WQT   ((size_t)0)
#define OFF_WKT   (OFF_WQT + 512*512*2)
#define OFF_WVT   (OFF_WKT + 512*512*2)
#define OFF_WOT   (OFF_WVT + 512*512*2)
#define OFF_W1T   (OFF_WOT + 512*512*2)
#define OFF_W2T   (OFF_W1T + (size_t)2048*512*2)
#define OFF_TEXTB (OFF_W2T + (size_t)512*2048*2)
#define OFF_KFB   (OFF_TEXTB + (size_t)640*512*2)
#define OFF_KNRM  (OFF_KFB + (size_t)640*512*2)
#define OFF_VPAD  (OFF_KNRM + (size_t)640*512*2)
#define OFF_PADM  (OFF_VPAD + (size_t)640*512*2)
#define OFF_ALLP  (OFF_PADM + 2560)
#define OFF_GATE  (OFF_ALLP + 256)
#define OFF_BYP   (OFF_GATE + (size_t)MROWS*4)
#define OFF_XB    (OFF_BYP + (size_t)MROWS*4)
#define OFF_BUFB  (OFF_XB + (size_t)MROWS*CDIM*2)
#define OFF_BUFC  (OFF_BUFB + (size_t)MROWS*CDIM*2)
#define OFF_H     (OFF_BUFC + (size_t)MROWS*CDIM*2)
#define WS_NEED   (OFF_H + (size_t)MROWS*HID*2)
// VT overlays HBUF (dead until the MLP phase): [B*NHEAD][64][96] bf16 = 768 KiB
#define OFF_VT    OFF_H

// ---------------- small helpers ----------------
__device__ __forceinline__ float waveReduceAdd(float v) {
#pragma unroll
    for (int m = 1; m < 64; m <<= 1) v += __shfl_xor(v, m);
    return v;
}
__device__ __forceinline__ float red16Max(float v) {
#pragma unroll
    for (int m = 1; m < 16; m <<= 1) v = fmaxf(v, __shfl_xor(v, m));
    return v;
}
__device__ __forceinline__ float red16Add(float v) {
#pragma unroll
    for (int m = 1; m < 16; m <<= 1) v += __shfl_xor(v, m);
    return v;
}
__device__ __forceinline__ float red16Min(float v) {
#pragma unroll
    for (int m = 1; m < 16; m <<= 1) v = fminf(v, __shfl_xor(v, m));
    return v;
}

// ---------------- prep mega-kernel ----------------
// blocks [0,3072): 6 weight transposes fp32 [R][C] -> bf16 [C][R]
// blocks [3072,3712): text rows -> bf16 (padded to 80/batch) + pad mask
// blocks [3712,3728): zero-fill VT pad slots t in [80,96)
__global__ __launch_bounds__(256) void prep_kernel(
    const float* __restrict__ Wq, const float* __restrict__ Wk,
    const float* __restrict__ Wv, const float* __restrict__ Wo,
    const float* __restrict__ W1, const float* __restrict__ W2,
    unsigned short* __restrict__ WQT, unsigned short* __restrict__ WKT,
    unsigned short* __restrict__ WVT, unsigned short* __restrict__ WOT,
    unsigned short* __restrict__ W1T, unsigned short* __restrict__ W2T,
    const float* __restrict__ text, unsigned short* __restrict__ textb,
    float* __restrict__ padm, unsigned short* __restrict__ vt)
{
    __shared__ float tile[32][33];
    __shared__ float sred[4];
    int b = blockIdx.x;
    const int tid = threadIdx.x;

    if (b >= 3712) {
        const int i = b - 3712;
        const int bh = i * 4 + (tid >> 6), d = tid & 63;
        uint4 z = {0u, 0u, 0u, 0u};
        uint4* p = (uint4*)(vt + ((size_t)bh * 64 + d) * 96 + 80);
        p[0] = z; p[1] = z;
        return;
    }
    if (b >= 3072) {
        const int r = b - 3072;                 // 0..639
        const int tb = r / TPAD, t = r % TPAD;
        if (t < TTXT) {
            const float2 v = ((const float2*)(text + ((size_t)(tb * TTXT + t)) * 512))[tid];
            float a = fabsf(v.x) + fabsf(v.y);
            a = waveReduceAdd(a);
            if ((tid & 63) == 0) sred[tid >> 6] = a;
            __syncthreads();
            const float asum = sred[0] + sred[1] + sred[2] + sred[3];
            ushort2 o; o.x = f2b(v.x); o.y = f2b(v.y);
            ((ushort2*)(textb + (size_t)r * 512))[tid] = o;
            if (tid == 0) padm[r] = (asum <= 1e-6f) ? 1.f : 0.f;
        } else {
            ushort2 z; z.x = 0; z.y = 0;
            ((ushort2*)(textb + (size_t)r * 512))[tid] = z;
            if (tid == 0) padm[r] = 1.f;
        }
        return;
    }

    const float* src; unsigned short* dst; int R, C, cx, ry;
    if (b < 1024)       { src = W1; dst = W1T; R = 512;  C = 2048; cx = b & 63; ry = b >> 6; }
    else if (b < 2048)  { b -= 1024; src = W2; dst = W2T; R = 2048; C = 512; cx = b & 15; ry = b >> 4; }
    else {
        b -= 2048; const int which = b >> 8; b &= 255;
        R = 512; C = 512; cx = b & 15; ry = b >> 4;
        src = (which == 0) ? Wq : (which == 1) ? Wk : (which == 2) ? Wv : Wo;
        dst = (which == 0) ? WQT : (which == 1) ? WKT : (which == 2) ? WVT : WOT;
    }
    const int tx = threadIdx.x & 31, ty = threadIdx.x >> 5;  // ty 0..7
    const int c0 = cx * 32, r0 = ry * 32;
#pragma unroll
    for (int i = 0; i < 32; i += 8)
        tile[ty + i][tx] = src[(size_t)(r0 + ty + i) * C + c0 + tx];
    __syncthreads();
#pragma unroll
    for (int i = 0; i < 32; i += 8)
        dst[(size_t)(c0 + ty + i) * R + r0 + tx] = f2b(tile[tx][ty + i]);
}

// ---------------- LN1 + gate ----------------
__global__ __launch_bounds__(128) void ln1_gate_kernel(
    const float* __restrict__ vin, const float* __restrict__ g1, const float* __restrict__ b1v,
    const float* __restrict__ Wg, const float* __restrict__ bg,
    unsigned short* __restrict__ xb, float* __restrict__ gate)
{
    __shared__ float sred[4];
    const int row = blockIdx.x, tid = threadIdx.x;
    const float4 v = *(const float4*)(vin + (size_t)row * 512 + tid * 4);
    float s = v.x + v.y + v.z + v.w;
    float s2 = v.x * v.x + v.y * v.y + v.z * v.z + v.w * v.w;
    s = waveReduceAdd(s); s2 = waveReduceAdd(s2);
    if ((tid & 63) == 0) { sred[tid >> 6] = s; sred[2 + (tid >> 6)] = s2; }
    __syncthreads();
    s = sred[0] + sred[1]; s2 = sred[2] + sred[3];
    const float mu = s * (1.f / 512.f);
    float var = s2 * (1.f / 512.f) - mu * mu;
    const float rs = rsqrtf(fmaxf(var, 0.f) + 1e-5f);
    const float4 gg = *(const float4*)(g1 + tid * 4);
    const float4 bb = *(const float4*)(b1v + tid * 4);
    const float x0 = (v.x - mu) * rs * gg.x + bb.x;
    const float x1 = (v.y - mu) * rs * gg.y + bb.y;
    const float x2 = (v.z - mu) * rs * gg.z + bb.z;
    const float x3 = (v.w - mu) * rs * gg.w + bb.w;
    ushort4 o; o.x = f2b(x0); o.y = f2b(x1); o.z = f2b(x2); o.w = f2b(x3);
    *(ushort4*)(xb + (size_t)row * 512 + tid * 4) = o;
    const float4 wg = *(const float4*)(Wg + tid * 4);
    float gp = x0 * wg.x + x1 * wg.y + x2 * wg.z + x3 * wg.w;
    gp = waveReduceAdd(gp);
    __syncthreads();
    if ((tid & 63) == 0) sred[tid >> 6] = gp;
    __syncthreads();
    if (tid == 0) {
        float z = sred[0] + sred[1] + bg[0];
        gate[row] = 1.f / (1.f + __expf(-z));
    }
}

// ---------------- LN2 ----------------
__global__ __launch_bounds__(128) void ln2_kernel(
    const unsigned short* __restrict__ yin, const float* __restrict__ g2, const float* __restrict__ b2v,
    unsigned short* __restrict__ yb)
{
    __shared__ float sred[4];
    const int row = blockIdx.x, tid = threadIdx.x;
    ushort4 u = *(const ushort4*)(yin + (size_t)row * 512 + tid * 4);
    float v0 = b2f(u.x), v1 = b2f(u.y), v2 = b2f(u.z), v3 = b2f(u.w);
    float s = v0 + v1 + v2 + v3;
    float s2 = v0 * v0 + v1 * v1 + v2 * v2 + v3 * v3;
    s = waveReduceAdd(s); s2 = waveReduceAdd(s2);
    if ((tid & 63) == 0) { sred[tid >> 6] = s; sred[2 + (tid >> 6)] = s2; }
    __syncthreads();
    s = sred[0] + sred[1]; s2 = sred[2] + sred[3];
    const float mu = s * (1.f / 512.f);
    float var = s2 * (1.f / 512.f) - mu * mu;
    const float rs = rsqrtf(fmaxf(var, 0.f) + 1e-5f);
    const float4 gg = *(const float4*)(g2 + tid * 4);
    const float4 bb = *(const float4*)(b2v + tid * 4);
    ushort4 o;
    o.x = f2b((v0 - mu) * rs * gg.x + bb.x);
    o.y = f2b((v1 - mu) * rs * gg.y + bb.y);
    o.z = f2b((v2 - mu) * rs * gg.z + bb.z);
    o.w = f2b((v3 - mu) * rs * gg.w + bb.w);
    *(ushort4*)(yb + (size_t)row * 512 + tid * 4) = o;
}

// ---------------- row l2-normalize bf16 -> bf16 (K only, 640 rows) ----------------
__global__ __launch_bounds__(128) void l2norm_kernel(
    const unsigned short* __restrict__ in, unsigned short* __restrict__ out)
{
    __shared__ float sred[2];
    const int row = blockIdx.x, tid = threadIdx.x;
    ushort4 u = *(const ushort4*)(in + (size_t)row * 512 + tid * 4);
    float v0 = b2f(u.x), v1 = b2f(u.y), v2 = b2f(u.z), v3 = b2f(u.w);
    float ss = v0 * v0 + v1 * v1 + v2 * v2 + v3 * v3;
    ss = waveReduceAdd(ss);
    if ((tid & 63) == 0) sred[tid >> 6] = ss;
    __syncthreads();
    ss = sred[0] + sred[1];
    const float inv = 1.f / fmaxf(sqrtf(ss), 1e-6f);
    ushort4 o;
    o.x = f2b(v0 * inv); o.y = f2b(v1 * inv); o.z = f2b(v2 * inv); o.w = f2b(v3 * inv);
    *(ushort4*)(out + (size_t)row * 512 + tid * 4) = o;
}

// ---------------- merged text K/V GEMM (128x128, M=640) ----------------
// grid (5,4,2): z=0 -> KFB (row-major bf16); z=1 -> VT direct (per-head transposed)
__global__ __launch_bounds__(256) void gemm_kv(
    const unsigned short* __restrict__ A,
    const unsigned short* __restrict__ BtK, const unsigned short* __restrict__ BtV,
    const float* __restrict__ bk, const float* __restrict__ bv,
    unsigned short* __restrict__ kfb, unsigned short* __restrict__ vt)
{
    const int K = 512, N = 512;
    const unsigned short* Bt = blockIdx.z ? BtV : BtK;
    const float* bias = blockIdx.z ? bv : bk;
    __shared__ unsigned short sA[128 * 64];
    __shared__ unsigned short sB[128 * 64];
    char* cA = (char*)sA;
    char* cB = (char*)sB;
    const int tid = threadIdx.x;
    const int lane = tid & 63, w = tid >> 6;
    const int g = lane >> 4, ln = lane & 15;
    const int WR = w >> 1, WC = w & 1;
    const int rowA0 = blockIdx.x * 128, colB0 = blockIdx.y * 128;

    f32x4 acc[4][4];
#pragma unroll
    for (int m = 0; m < 4; ++m)
#pragma unroll
        for (int n = 0; n < 4; ++n) acc[m][n] = (f32x4){0.f, 0.f, 0.f, 0.f};

    for (int k0 = 0; k0 < K; k0 += 64) {
        __syncthreads();
#pragma unroll
        for (int i = 0; i < 4; ++i) {
            int c = tid + i * 256;
            int row = c >> 3, kc = c & 7;
            int kcs = kc ^ (row & 7);
            gload16(A + (size_t)(rowA0 + row) * K + k0 + kcs * 8, cA + c * 16);
            gload16(Bt + (size_t)(colB0 + row) * K + k0 + kcs * 8, cB + c * 16);
        }
        __syncthreads();
#pragma unroll
        for (int kk = 0; kk < 2; ++kk) {
            short8 af[4], bf[4];
#pragma unroll
            for (int m = 0; m < 4; ++m) {
                int row = WR * 64 + m * 16 + ln;
                af[m] = *(const short8*)(cA + row * 128 + ((kk * 64 + g * 16) ^ ((row & 7) << 4)));
            }
#pragma unroll
            for (int n = 0; n < 4; ++n) {
                int col = WC * 64 + n * 16 + ln;
                bf[n] = *(const short8*)(cB + col * 128 + ((kk * 64 + g * 16) ^ ((col & 7) << 4)));
            }
#pragma unroll
            for (int m = 0; m < 4; ++m)
#pragma unroll
                for (int n = 0; n < 4; ++n)
                    acc[m][n] = __builtin_amdgcn_mfma_f32_16x16x32_bf16(af[m], bf[n], acc[m][n], 0, 0, 0);
        }
    }

#pragma unroll
    for (int m = 0; m < 4; ++m) {
        const int rbase = rowA0 + WR * 64 + m * 16 + g * 4;
#pragma unroll
        for (int n = 0; n < 4; ++n) {
            const int col = colB0 + WC * 64 + n * 16 + ln;
            const float bcol = bias[col];
#pragma unroll
            for (int i = 0; i < 4; ++i) {
                const int row = rbase + i;
                const float v = acc[m][n][i] + bcol;
                if (blockIdx.z == 0) {
                    kfb[(size_t)row * N + col] = f2b(v);
                } else {
                    const int tb = row / TPAD, t = row - tb * TPAD;
                    const int h = col >> 6, d = col & 63;
                    vt[((size_t)(tb * NHEAD + h) * 64 + d) * 96 + t] = f2b(v);
                }
            }
        }
    }
}

// ---------------- 256x256 bf16 MFMA GEMM, BK=32 / 64 KiB LDS / 2 blocks per CU ----------------
// Occupancy lever: 64 KiB LDS (2 bufs x [A 16KB + B 16KB]) -> 2 resident blocks/CU
// (launch_bounds(512,4)); one block's barrier/drain overlaps the other's MFMA.
// Round-8 low-barrier ledger kept: stage(t+1) into buf^1 (never live), one
// vmcnt(0)+barrier per tile. Bank swizzle for 64B rows: unit ^= (row>>1)&3 —
// per-thread-constant on reads (g ^ (ln>>1)&3), exactly 2-way aliasing (free).
template<int EPI>
__global__ __launch_bounds__(512, 4) void gemm256(
    const unsigned short* __restrict__ A, const unsigned short* __restrict__ Bt,
    const float* __restrict__ bias,
    unsigned short* __restrict__ outb, float* __restrict__ outf,
    int M, int N, int K,
    const unsigned short* __restrict__ xres, const float* __restrict__ gate,
    const float* __restrict__ byp, const unsigned short* __restrict__ yres,
    const float* __restrict__ alphaPtr, int gxM, int gyN)
{
    __shared__ unsigned short lds[2][2][8192];    // [buf][A/B][256*32] = 64 KiB
    const int tid = threadIdx.x;
    const int lane = tid & 63, w = tid >> 6;
    const int g = lane >> 4, ln = lane & 15;
    const int wr = w >> 2, wc = w & 3;

    // XCD-chunked bijective swizzle
    int bm, bn;
    {
        const int L = (int)blockIdx.x;
        const int xcd = L & 7, j = L >> 3;
        const int rl = j / gyN;
        bn = j - rl * gyN;
        bm = xcd * (gxM >> 3) + rl;
    }
    const int rowA0 = bm * 256, colB0 = bn * 256;
    const int nt = K >> 5;                        // BK = 32

    auto stageA = [&](int t) {
        const int buf = t & 1;
#pragma unroll
        for (int r = 0; r < 2; ++r) {
            const int c = tid + r * 512;          // 0..1023 16B slots (16 KB)
            const int row = c >> 2, kc = c & 3;
            const int kcs = kc ^ ((row >> 1) & 3);
            gload16(A + (size_t)(rowA0 + row) * K + (t << 5) + (kcs << 3),
                    (char*)&lds[buf][0][0] + c * 16);
        }
    };
    auto stageB = [&](int t) {
        const int buf = t & 1;
#pragma unroll
        for (int r = 0; r < 2; ++r) {
            const int c = tid + r * 512;
            const int row = c >> 2, kc = c & 3;
            const int kcs = kc ^ ((row >> 1) & 3);
            gload16(Bt + (size_t)(colB0 + row) * K + (t << 5) + (kcs << 3),
                    (char*)&lds[buf][1][0] + c * 16);
        }
    };

    f32x4 acc[8][4];
#pragma unroll
    for (int m = 0; m < 8; ++m)
#pragma unroll
        for (int n = 0; n < 4; ++n) acc[m][n] = (f32x4){0.f, 0.f, 0.f, 0.f};

    // prologue: stage tile 0; drain; barrier
    stageA(0); stageB(0);
    asm volatile("s_waitcnt vmcnt(0)" ::: "memory");
    __builtin_amdgcn_s_barrier();

    const int swz = (g ^ ((ln >> 1) & 3)) << 4;   // per-thread-constant unit swizzle
    const int arow = (wr * 128 + ln) * 64 + swz;  // + m*1024 (16 rows * 64B)
    const int brow = (wc * 64 + ln) * 64 + swz;   // + n*1024

    short8 af[8], bf[4];

#pragma unroll 2
    for (int t = 0; t < nt; ++t) {
        const char* lA = (const char*)&lds[t & 1][0][0];
        const char* lB = (const char*)&lds[t & 1][1][0];
        const bool pf = (t + 1 < nt);

#pragma unroll
        for (int m = 0; m < 8; ++m) af[m] = *(const short8*)(lA + arow + m * 1024);
#pragma unroll
        for (int n = 0; n < 4; ++n) bf[n] = *(const short8*)(lB + brow + n * 1024);
        if (pf) { stageA(t + 1); stageB(t + 1); }
        __builtin_amdgcn_s_setprio(1);
#pragma unroll
        for (int m = 0; m < 8; ++m)
#pragma unroll
            for (int n = 0; n < 4; ++n)
                acc[m][n] = __builtin_amdgcn_mfma_f32_16x16x32_bf16(af[m], bf[n], acc[m][n], 0, 0, 0);
        __builtin_amdgcn_s_setprio(0);

        // tile boundary: t+1 fully landed; all waves past tile-t reads
        if (pf) {
            asm volatile("s_waitcnt vmcnt(0)" ::: "memory");
            __builtin_amdgcn_s_barrier();
        }
    }

    // ---- epilogue ----
    const float alpha = (EPI == 1) ? *alphaPtr : 0.f;
#pragma unroll
    for (int m = 0; m < 8; ++m) {
        const int rbase = rowA0 + wr * 128 + m * 16 + g * 4;
#pragma unroll
        for (int n = 0; n < 4; ++n) {
            const int col = colB0 + wc * 64 + n * 16 + ln;
            const float bcol = bias[col];
#pragma unroll
            for (int i = 0; i < 4; ++i) {
                const int row = rbase + i;
                const float v = acc[m][n][i] + bcol;
                if (EPI == 0) {
                    outb[(size_t)row * N + col] = f2b(v);
                } else if (EPI == 1) {
                    float yp = b2f(xres[(size_t)row * N + col]) + alpha * gate[row] * byp[row] * v;
                    outb[(size_t)row * N + col] = f2b(yp);
                } else if (EPI == 2) {
                    const float u2 = 2.f * v * (0.7978845608f + 0.0356774081f * v * v);
                    const float tt = 1.f - 2.f / (__expf(u2) + 1.f);
                    outb[(size_t)row * N + col] = f2b(0.5f * v * (1.f + tt));
                } else {
                    outf[(size_t)row * N + col] = b2f(yres[(size_t)row * N + col]) + v;
                }
            }
        }
    }
}

// ---------------- fused attention (q-l2norm + allpad fused in) ----------------
// grid: (NTOK/16, B), block 256 = 4 waves; each wave: same 16 rows, heads {w, w+4}.
__global__ __launch_bounds__(256) void attn_kernel(
    const unsigned short* __restrict__ qn,   // [MROWS,512] raw q, bf16
    const unsigned short* __restrict__ kn,   // [B,80,512] l2-normed k, bf16
    const unsigned short* __restrict__ vt,   // [B*8][64][96] per-head V^T, bf16
    const float* __restrict__ padm,          // [B,80] 1.0 = pad
    const float* __restrict__ lscPtr,
    unsigned short* __restrict__ aligned,    // [MROWS,512] bf16
    float* __restrict__ bypass)              // [MROWS]
{
    const int b = blockIdx.y;
    const int n0 = blockIdx.x * 16;
    const int tid = threadIdx.x;
    const int w = tid >> 6, lane = tid & 63, g = lane >> 4, ln = lane & 15;
    __shared__ unsigned short s_p[4][16][104];
    __shared__ float s_conf[4][16];
    __shared__ float s_inv[16];

    // pad-mask of this lane's 5 t-columns (depends only on ln)
    float pm[5];
#pragma unroll
    for (int tt = 0; tt < 5; ++tt) {
        int t = ln + tt * 16;
        pm[tt] = (t < TTXT) ? padm[b * TPAD + t] : 1.f;
    }
    // all-pad check (fused allpad): min over t<77 of padm
    {
        float pmn = fminf(fminf(pm[0], pm[1]), fminf(fminf(pm[2], pm[3]), pm[4]));
        pmn = red16Min(pmn);
        if (pmn > 0.5f) {
            uint4 z = {0u, 0u, 0u, 0u};
#pragma unroll
            for (int j = 0; j < 4; ++j) {
                int id = tid + j * 256;
                int row = id >> 6, c8 = id & 63;
                *(uint4*)(aligned + ((size_t)(b * NTOK + n0 + row)) * 512 + c8 * 8) = z;
            }
            if (tid < 16) bypass[b * NTOK + n0 + tid] = 0.f;
            return;
        }
    }

    // ---- q-norm preamble: 16 rows x 512 ch; thread (r=tid>>4, seg=tid&15) ----
    {
        const int r = tid >> 4, seg = tid & 15;
        const unsigned short* qp = qn + ((size_t)(b * NTOK + n0 + r)) * 512 + seg * 32;
        float ss = 0.f;
#pragma unroll
        for (int j = 0; j < 4; ++j) {
            short8 u = *(const short8*)(qp + j * 8);
#pragma unroll
            for (int e = 0; e < 8; ++e) {
                float f = b2f(((const unsigned short*)&u)[e]);
                ss += f * f;
            }
        }
        ss = red16Add(ss);
        if (seg == 0) s_inv[r] = 1.f / fmaxf(sqrtf(ss), 1e-6f);
    }

    float lscale;
    {
        float ls = *lscPtr;
        ls = fminf(fmaxf(ls, -2.f), 2.f);
        lscale = __expf(ls) * 0.125f;
    }

    for (int j = g; j < 24; j += 4) s_p[w][ln][80 + j] = 0;
    __syncthreads();                               // s_inv ready

    float conf_acc[4] = {0.f, 0.f, 0.f, 0.f};
    const size_t qrow = ((size_t)(b * NTOK + n0 + ln)) * 512;

#pragma unroll
    for (int hh = 0; hh < 2; ++hh) {
        const int h = w + hh * 4;
        short8 a0 = *(const short8*)(qn + qrow + h * 64 + g * 8);
        short8 a1 = *(const short8*)(qn + qrow + h * 64 + 32 + g * 8);
        f32x4 sim[5];
#pragma unroll
        for (int tt = 0; tt < 5; ++tt) {
            const size_t kbase = ((size_t)(b * TPAD + tt * 16 + ln)) * 512 + h * 64;
            short8 b0 = *(const short8*)(kn + kbase + g * 8);
            short8 b1 = *(const short8*)(kn + kbase + 32 + g * 8);
            f32x4 c = (f32x4){0.f, 0.f, 0.f, 0.f};
            c = __builtin_amdgcn_mfma_f32_16x16x32_bf16(a0, b0, c, 0, 0, 0);
            c = __builtin_amdgcn_mfma_f32_16x16x32_bf16(a1, b1, c, 0, 0, 0);
            sim[tt] = c;
        }
#pragma unroll
        for (int i = 0; i < 4; ++i) {
            const float qs = lscale * s_inv[g * 4 + i];   // row = g*4+i (C/D layout)
            float v[5];
#pragma unroll
            for (int tt = 0; tt < 5; ++tt)
                v[tt] = (pm[tt] == 0.f) ? sim[tt][i] * qs : NEGINF;

            float lm = v[0];
#pragma unroll
            for (int tt = 1; tt < 5; ++tt) lm = fmaxf(lm, v[tt]);
            const float m1 = red16Max(lm);
            float lm2 = -3.0e38f;
#pragma unroll
            for (int tt = 0; tt < 5; ++tt) if (v[tt] < m1) lm2 = fmaxf(lm2, v[tt]);
            const float m2 = red16Max(lm2);
            float lm3 = -3.0e38f;
#pragma unroll
            for (int tt = 0; tt < 5; ++tt) if (v[tt] < m2) lm3 = fmaxf(lm3, v[tt]);
            const float m3 = red16Max(lm3);
            // packed count reduction: c1 + 128*c2 (both <= 80 < 128)
            float lc = 0.f;
#pragma unroll
            for (int tt = 0; tt < 5; ++tt) {
                if (v[tt] >= m1) lc += 1.f;
                if (v[tt] >= m2) lc += 128.f;
            }
            const float cpk = red16Add(lc);
            const float c2 = floorf(cpk * (1.f / 128.f));
            const float c1 = cpk - 128.f * c2;
            const float th = (c1 >= 3.f) ? m1 : ((c2 >= 3.f) ? m2 : m3);

            float p[5], lsum = 0.f, lcnt = 0.f;
#pragma unroll
            for (int tt = 0; tt < 5; ++tt) {
                float pv = (v[tt] >= th) ? __expf(v[tt] - m1) : 0.f;
                p[tt] = pv;
                lsum += pv;
                lcnt += (pv > 0.f) ? 1.f : 0.f;
            }
            const float psum = red16Add(lsum);
            const float pcnt = red16Add(lcnt);
            const float inv = 1.f / fmaxf(psum, 1e-20f);

            float lmaxp = 0.f, lent = 0.f;
#pragma unroll
            for (int tt = 0; tt < 5; ++tt) {
                float a = p[tt] * inv;
                p[tt] = a;
                lmaxp = fmaxf(lmaxp, a);
                if (a > 0.f) {
                    float pp = fmaxf(a, 1e-8f);
                    lent += -pp * __logf(pp);
                }
            }
            const float maxp = red16Max(lmaxp);
            float ent = red16Add(lent);
            ent += (77.f - pcnt) * 1.8420680744e-7f;
            const float teff = fmaxf(pcnt, 2.f);
            const float entropy = fmaxf(ent / __logf(teff), 0.f);
            const float confh = fminf(fmaxf(maxp * (1.f - entropy), 0.f), 1.f);
            conf_acc[i] += confh;

#pragma unroll
            for (int tt = 0; tt < 5; ++tt)
                s_p[w][g * 4 + i][ln + tt * 16] = f2b(p[tt]);
        }
        short8 af[3];
#pragma unroll
        for (int k = 0; k < 3; ++k)
            af[k] = *(const short8*)(&s_p[w][ln][k * 32 + g * 8]);
        const size_t vtb = ((size_t)(b * NHEAD + h)) * 64;
#pragma unroll
        for (int n = 0; n < 4; ++n) {
            f32x4 o = (f32x4){0.f, 0.f, 0.f, 0.f};
#pragma unroll
            for (int k = 0; k < 3; ++k) {
                short8 bf = *(const short8*)(vt + (vtb + n * 16 + ln) * 96 + k * 32 + g * 8);
                o = __builtin_amdgcn_mfma_f32_16x16x32_bf16(af[k], bf, o, 0, 0, 0);
            }
#pragma unroll
            for (int i = 0; i < 4; ++i)
                aligned[((size_t)(b * NTOK + n0 + g * 4 + i)) * 512 + h * 64 + n * 16 + ln] =
                    f2b(o[i]);
        }
    }

    if (ln == 0) {
#pragma unroll
        for (int i = 0; i < 4; ++i) s_conf[w][g * 4 + i] = conf_acc[i];
    }
    __syncthreads();
    if (tid < 16) {
        float c = (s_conf[0][tid] + s_conf[1][tid] + s_conf[2][tid] + s_conf[3][tid]) * 0.125f;
        bypass[b * NTOK + n0 + tid] = (c >= 0.35f) ? 1.f : 0.f;
    }
}

// ---------------- host side ----------------
extern "C" void kernel_launch(void* const* d_in, const int* in_sizes, int n_in,
                              void* d_out, int out_size, void* d_ws, size_t ws_size,
                              hipStream_t stream)
{
    (void)in_sizes; (void)n_in; (void)out_size;
    if (ws_size < WS_NEED) return;

    const float* visual = (const float*)d_in[0];
    const float* text   = (const float*)d_in[1];
    const float* ln1_g  = (const float*)d_in[2];
    const float* ln1_b  = (const float*)d_in[3];
    const float* ln2_g  = (const float*)d_in[4];
    const float* ln2_b  = (const float*)d_in[5];
    const float* Wq = (const float*)d_in[6];   const float* bq = (const float*)d_in[7];
    const float* Wk = (const float*)d_in[8];   const float* bk = (const float*)d_in[9];
    const float* Wv = (const float*)d_in[10];  const float* bv = (const float*)d_in[11];
    const float* Wo = (const float*)d_in[12];  const float* bo = (const float*)d_in[13];
    const float* Wg = (const float*)d_in[14];  const float* bg = (const float*)d_in[15];
    const float* W1 = (const float*)d_in[16];  const float* b1 = (const float*)d_in[17];
    const float* W2 = (const float*)d_in[18];  const float* b2 = (const float*)d_in[19];
    const float* lsc = (const float*)d_in[20];
    const float* alp = (const float*)d_in[21];

    char* ws = (char*)d_ws;
    unsigned short* WQT  = (unsigned short*)(ws + OFF_WQT);
    unsigned short* WKT  = (unsigned short*)(ws + OFF_WKT);
    unsigned short* WVT  = (unsigned short*)(ws + OFF_WVT);
    unsigned short* WOT  = (unsigned short*)(ws + OFF_WOT);
    unsigned short* W1T  = (unsigned short*)(ws + OFF_W1T);
    unsigned short* W2T  = (unsigned short*)(ws + OFF_W2T);
    unsigned short* TEXTB = (unsigned short*)(ws + OFF_TEXTB);
    unsigned short* KFB  = (unsigned short*)(ws + OFF_KFB);
    unsigned short* KNRM = (unsigned short*)(ws + OFF_KNRM);
    float* PADM = (float*)(ws + OFF_PADM);
    float* GATE = (float*)(ws + OFF_GATE);
    float* BYP  = (float*)(ws + OFF_BYP);
    unsigned short* XB   = (unsigned short*)(ws + OFF_XB);
    unsigned short* BUFB = (unsigned short*)(ws + OFF_BUFB);
    unsigned short* BUFC = (unsigned short*)(ws + OFF_BUFC);
    unsigned short* HBUF = (unsigned short*)(ws + OFF_H);
    unsigned short* VT   = (unsigned short*)(ws + OFF_VT);   // overlays HBUF
    float* out = (float*)d_out;

    // 1) prep: all weight transposes + text bf16/padmask + VT pad zero-fill
    prep_kernel<<<3728, 256, 0, stream>>>(Wq, Wk, Wv, Wo, W1, W2,
                                          WQT, WKT, WVT, WOT, W1T, W2T,
                                          text, TEXTB, PADM, VT);

    // 2) LN1 + gate
    ln1_gate_kernel<<<MROWS, 128, 0, stream>>>(visual, ln1_g, ln1_b, Wg, bg, XB, GATE);

    // 3) text K/V projections in one launch (V writes VT directly) + K l2norm
    gemm_kv<<<dim3(5, 4, 2), 256, 0, stream>>>(TEXTB, WKT, WVT, bk, bv, KFB, VT);
    l2norm_kernel<<<640, 128, 0, stream>>>(KFB, KNRM);

    // 4) Q projection (raw q -> BUFB; l2norm fused into attn)
    gemm256<0><<<dim3(128 * 2), 512, 0, stream>>>(XB, WQT, bq, BUFB, nullptr, MROWS, 512, 512,
                                                  nullptr, nullptr, nullptr, nullptr, nullptr,
                                                  128, 2);

    // 5) fused attention (q-norm + allpad inside) -> aligned (BUFC), bypass
    attn_kernel<<<dim3(NTOK / 16, BATCH), 256, 0, stream>>>(BUFB, KNRM, VT, PADM, lsc,
                                                            BUFC, BYP);

    // 6) Wo projection + gated residual -> ypre (BUFB)
    gemm256<1><<<dim3(128 * 2), 512, 0, stream>>>(BUFC, WOT, bo, BUFB, nullptr, MROWS, 512, 512,
                                                  XB, GATE, BYP, nullptr, alp, 128, 2);

    // 7) LN2 -> yb (XB)
    ln2_kernel<<<MROWS, 128, 0, stream>>>(BUFB, ln2_g, ln2_b, XB);

    // 8) MLP (HBUF reuses the VT region — VT is dead by now)
    gemm256<2><<<dim3(128 * 8), 512, 0, stream>>>(XB, W1T, b1, HBUF, nullptr, MROWS, HID, 512,
                                                  nullptr, nullptr, nullptr, nullptr, nullptr,
                                                  128, 8);
    gemm256<3><<<dim3(128 * 2), 512, 0, stream>>>(HBUF, W2T, b2, nullptr, out, MROWS, 512, HID,
                                                  nullptr, nullptr, nullptr, XB, nullptr,
                                                  128, 2);
}

// Round 13
// 385.572 us; speedup vs baseline: 5.6103x; 5.6103x over previous
//
#include <hip/hip_runtime.h>
#include <stdint.h>

// ---------------- problem constants ----------------
#define BATCH 8
#define NTOK 4096          // 64*64
#define CDIM 512
#define TTXT 77
#define TPAD 80
#define NHEAD 8
#define HDIM 64
#define HID 2048           // 4*C
#define MROWS 32768        // B*NTOK
#define NEGINF (-1e30f)

typedef __attribute__((ext_vector_type(8))) short short8;
typedef __attribute__((ext_vector_type(4))) float f32x4;

__device__ __forceinline__ float b2f(unsigned short u) {
    union { unsigned int i; float f; } x; x.i = ((unsigned int)u) << 16; return x.f;
}
__device__ __forceinline__ unsigned short f2b(float f) {
    union { float f; unsigned int i; } x; x.f = f;
    unsigned int i = x.i;
    return (unsigned short)((i + 0x7fffu + ((i >> 16) & 1u)) >> 16);
}

// async global->LDS, 16B per lane; LDS dest must be linear in lane order
__device__ __forceinline__ void gload16(const void* g, void* l) {
    __builtin_amdgcn_global_load_lds(
        (const __attribute__((address_space(1))) unsigned int*)g,
        (__attribute__((address_space(3))) unsigned int*)l, 16, 0, 0);
}

// ---------------- workspace layout (bytes) ----------------
#define OFF_WQT   ((size_t)0)
#define OFF_WKT   (OFF_WQT + 512*512*2)
#define OFF_WVT   (OFF_WKT + 512*512*2)
#define OFF_WOT   (OFF_WVT + 512*512*2)
#define OFF_W1T   (OFF_WOT + 512*512*2)
#define OFF_W2T   (OFF_W1T + (size_t)2048*512*2)
#define OFF_TEXTB (OFF_W2T + (size_t)512*2048*2)
#define OFF_KFB   (OFF_TEXTB + (size_t)640*512*2)
#define OFF_KNRM  (OFF_KFB + (size_t)640*512*2)
#define OFF_VPAD  (OFF_KNRM + (size_t)640*512*2)
#define OFF_PADM  (OFF_VPAD + (size_t)640*512*2)
#define OFF_ALLP  (OFF_PADM + 2560)
#define OFF_GATE  (OFF_ALLP + 256)
#define OFF_BYP   (OFF_GATE + (size_t)MROWS*4)
#define OFF_XB    (OFF_BYP + (size_t)MROWS*4)
#define OFF_BUFB  (OFF_XB + (size_t)MROWS*CDIM*2)
#define OFF_BUFC  (OFF_BUFB + (size_t)MROWS*CDIM*2)
#define OFF_H     (OFF_BUFC + (size_t)MROWS*CDIM*2)
#define WS_NEED   (OFF_H + (size_t)MROWS*HID*2)
// VT overlays HBUF (dead until the MLP phase): [B*NHEAD][64][96] bf16 = 768 KiB
#define OFF_VT    OFF_H

// ---------------- small helpers ----------------
__device__ __forceinline__ float waveReduceAdd(float v) {
#pragma unroll
    for (int m = 1; m < 64; m <<= 1) v += __shfl_xor(v, m);
    return v;
}
__device__ __forceinline__ float red16Max(float v) {
#pragma unroll
    for (int m = 1; m < 16; m <<= 1) v = fmaxf(v, __shfl_xor(v, m));
    return v;
}
__device__ __forceinline__ float red16Add(float v) {
#pragma unroll
    for (int m = 1; m < 16; m <<= 1) v += __shfl_xor(v, m);
    return v;
}
__device__ __forceinline__ float red16Min(float v) {
#pragma unroll
    for (int m = 1; m < 16; m <<= 1) v = fminf(v, __shfl_xor(v, m));
    return v;
}

// ---------------- prep mega-kernel ----------------
// blocks [0,3072): 6 weight transposes fp32 [R][C] -> bf16 [C][R]
// blocks [3072,3712): text rows -> bf16 (padded to 80/batch) + pad mask
// blocks [3712,3728): zero-fill VT pad slots t in [80,96)
__global__ __launch_bounds__(256) void prep_kernel(
    const float* __restrict__ Wq, const float* __restrict__ Wk,
    const float* __restrict__ Wv, const float* __restrict__ Wo,
    const float* __restrict__ W1, const float* __restrict__ W2,
    unsigned short* __restrict__ WQT, unsigned short* __restrict__ WKT,
    unsigned short* __restrict__ WVT, unsigned short* __restrict__ WOT,
    unsigned short* __restrict__ W1T, unsigned short* __restrict__ W2T,
    const float* __restrict__ text, unsigned short* __restrict__ textb,
    float* __restrict__ padm, unsigned short* __restrict__ vt)
{
    __shared__ float tile[32][33];
    __shared__ float sred[4];
    int b = blockIdx.x;
    const int tid = threadIdx.x;

    if (b >= 3712) {
        const int i = b - 3712;
        const int bh = i * 4 + (tid >> 6), d = tid & 63;
        uint4 z = {0u, 0u, 0u, 0u};
        uint4* p = (uint4*)(vt + ((size_t)bh * 64 + d) * 96 + 80);
        p[0] = z; p[1] = z;
        return;
    }
    if (b >= 3072) {
        const int r = b - 3072;                 // 0..639
        const int tb = r / TPAD, t = r % TPAD;
        if (t < TTXT) {
            const float2 v = ((const float2*)(text + ((size_t)(tb * TTXT + t)) * 512))[tid];
            float a = fabsf(v.x) + fabsf(v.y);
            a = waveReduceAdd(a);
            if ((tid & 63) == 0) sred[tid >> 6] = a;
            __syncthreads();
            const float asum = sred[0] + sred[1] + sred[2] + sred[3];
            ushort2 o; o.x = f2b(v.x); o.y = f2b(v.y);
            ((ushort2*)(textb + (size_t)r * 512))[tid] = o;
            if (tid == 0) padm[r] = (asum <= 1e-6f) ? 1.f : 0.f;
        } else {
            ushort2 z; z.x = 0; z.y = 0;
            ((ushort2*)(textb + (size_t)r * 512))[tid] = z;
            if (tid == 0) padm[r] = 1.f;
        }
        return;
    }

    const float* src; unsigned short* dst; int R, C, cx, ry;
    if (b < 1024)       { src = W1; dst = W1T; R = 512;  C = 2048; cx = b & 63; ry = b >> 6; }
    else if (b < 2048)  { b -= 1024; src = W2; dst = W2T; R = 2048; C = 512; cx = b & 15; ry = b >> 4; }
    else {
        b -= 2048; const int which = b >> 8; b &= 255;
        R = 512; C = 512; cx = b & 15; ry = b >> 4;
        src = (which == 0) ? Wq : (which == 1) ? Wk : (which == 2) ? Wv : Wo;
        dst = (which == 0) ? WQT : (which == 1) ? WKT : (which == 2) ? WVT : WOT;
    }
    const int tx = threadIdx.x & 31, ty = threadIdx.x >> 5;  // ty 0..7
    const int c0 = cx * 32, r0 = ry * 32;
#pragma unroll
    for (int i = 0; i < 32; i += 8)
        tile[ty + i][tx] = src[(size_t)(r0 + ty + i) * C + c0 + tx];
    __syncthreads();
#pragma unroll
    for (int i = 0; i < 32; i += 8)
        dst[(size_t)(c0 + ty + i) * R + r0 + tx] = f2b(tile[tx][ty + i]);
}

// ---------------- LN1 + gate ----------------
__global__ __launch_bounds__(128) void ln1_gate_kernel(
    const float* __restrict__ vin, const float* __restrict__ g1, const float* __restrict__ b1v,
    const float* __restrict__ Wg, const float* __restrict__ bg,
    unsigned short* __restrict__ xb, float* __restrict__ gate)
{
    __shared__ float sred[4];
    const int row = blockIdx.x, tid = threadIdx.x;
    const float4 v = *(const float4*)(vin + (size_t)row * 512 + tid * 4);
    float s = v.x + v.y + v.z + v.w;
    float s2 = v.x * v.x + v.y * v.y + v.z * v.z + v.w * v.w;
    s = waveReduceAdd(s); s2 = waveReduceAdd(s2);
    if ((tid & 63) == 0) { sred[tid >> 6] = s; sred[2 + (tid >> 6)] = s2; }
    __syncthreads();
    s = sred[0] + sred[1]; s2 = sred[2] + sred[3];
    const float mu = s * (1.f / 512.f);
    float var = s2 * (1.f / 512.f) - mu * mu;
    const float rs = rsqrtf(fmaxf(var, 0.f) + 1e-5f);
    const float4 gg = *(const float4*)(g1 + tid * 4);
    const float4 bb = *(const float4*)(b1v + tid * 4);
    const float x0 = (v.x - mu) * rs * gg.x + bb.x;
    const float x1 = (v.y - mu) * rs * gg.y + bb.y;
    const float x2 = (v.z - mu) * rs * gg.z + bb.z;
    const float x3 = (v.w - mu) * rs * gg.w + bb.w;
    ushort4 o; o.x = f2b(x0); o.y = f2b(x1); o.z = f2b(x2); o.w = f2b(x3);
    *(ushort4*)(xb + (size_t)row * 512 + tid * 4) = o;
    const float4 wg = *(const float4*)(Wg + tid * 4);
    float gp = x0 * wg.x + x1 * wg.y + x2 * wg.z + x3 * wg.w;
    gp = waveReduceAdd(gp);
    __syncthreads();
    if ((tid & 63) == 0) sred[tid >> 6] = gp;
    __syncthreads();
    if (tid == 0) {
        float z = sred[0] + sred[1] + bg[0];
        gate[row] = 1.f / (1.f + __expf(-z));
    }
}

// ---------------- LN2 ----------------
__global__ __launch_bounds__(128) void ln2_kernel(
    const unsigned short* __restrict__ yin, const float* __restrict__ g2, const float* __restrict__ b2v,
    unsigned short* __restrict__ yb)
{
    __shared__ float sred[4];
    const int row = blockIdx.x, tid = threadIdx.x;
    ushort4 u = *(const ushort4*)(yin + (size_t)row * 512 + tid * 4);
    float v0 = b2f(u.x), v1 = b2f(u.y), v2 = b2f(u.z), v3 = b2f(u.w);
    float s = v0 + v1 + v2 + v3;
    float s2 = v0 * v0 + v1 * v1 + v2 * v2 + v3 * v3;
    s = waveReduceAdd(s); s2 = waveReduceAdd(s2);
    if ((tid & 63) == 0) { sred[tid >> 6] = s; sred[2 + (tid >> 6)] = s2; }
    __syncthreads();
    s = sred[0] + sred[1]; s2 = sred[2] + sred[3];
    const float mu = s * (1.f / 512.f);
    float var = s2 * (1.f / 512.f) - mu * mu;
    const float rs = rsqrtf(fmaxf(var, 0.f) + 1e-5f);
    const float4 gg = *(const float4*)(g2 + tid * 4);
    const float4 bb = *(const float4*)(b2v + tid * 4);
    ushort4 o;
    o.x = f2b((v0 - mu) * rs * gg.x + bb.x);
    o.y = f2b((v1 - mu) * rs * gg.y + bb.y);
    o.z = f2b((v2 - mu) * rs * gg.z + bb.z);
    o.w = f2b((v3 - mu) * rs * gg.w + bb.w);
    *(ushort4*)(yb + (size_t)row * 512 + tid * 4) = o;
}

// ---------------- row l2-normalize bf16 -> bf16 (K only, 640 rows) ----------------
__global__ __launch_bounds__(128) void l2norm_kernel(
    const unsigned short* __restrict__ in, unsigned short* __restrict__ out)
{
    __shared__ float sred[2];
    const int row = blockIdx.x, tid = threadIdx.x;
    ushort4 u = *(const ushort4*)(in + (size_t)row * 512 + tid * 4);
    float v0 = b2f(u.x), v1 = b2f(u.y), v2 = b2f(u.z), v3 = b2f(u.w);
    float ss = v0 * v0 + v1 * v1 + v2 * v2 + v3 * v3;
    ss = waveReduceAdd(ss);
    if ((tid & 63) == 0) sred[tid >> 6] = ss;
    __syncthreads();
    ss = sred[0] + sred[1];
    const float inv = 1.f / fmaxf(sqrtf(ss), 1e-6f);
    ushort4 o;
    o.x = f2b(v0 * inv); o.y = f2b(v1 * inv); o.z = f2b(v2 * inv); o.w = f2b(v3 * inv);
    *(ushort4*)(out + (size_t)row * 512 + tid * 4) = o;
}

// ---------------- merged text K/V GEMM (128x128, M=640) ----------------
// grid (5,4,2): z=0 -> KFB (row-major bf16); z=1 -> VT direct (per-head transposed)
__global__ __launch_bounds__(256) void gemm_kv(
    const unsigned short* __restrict__ A,
    const unsigned short* __restrict__ BtK, const unsigned short* __restrict__ BtV,
    const float* __restrict__ bk, const float* __restrict__ bv,
    unsigned short* __restrict__ kfb, unsigned short* __restrict__ vt)
{
    const int K = 512, N = 512;
    const unsigned short* Bt = blockIdx.z ? BtV : BtK;
    const float* bias = blockIdx.z ? bv : bk;
    __shared__ unsigned short sA[128 * 64];
    __shared__ unsigned short sB[128 * 64];
    char* cA = (char*)sA;
    char* cB = (char*)sB;
    const int tid = threadIdx.x;
    const int lane = tid & 63, w = tid >> 6;
    const int g = lane >> 4, ln = lane & 15;
    const int WR = w >> 1, WC = w & 1;
    const int rowA0 = blockIdx.x * 128, colB0 = blockIdx.y * 128;

    f32x4 acc[4][4];
#pragma unroll
    for (int m = 0; m < 4; ++m)
#pragma unroll
        for (int n = 0; n < 4; ++n) acc[m][n] = (f32x4){0.f, 0.f, 0.f, 0.f};

    for (int k0 = 0; k0 < K; k0 += 64) {
        __syncthreads();
#pragma unroll
        for (int i = 0; i < 4; ++i) {
            int c = tid + i * 256;
            int row = c >> 3, kc = c & 7;
            int kcs = kc ^ (row & 7);
            gload16(A + (size_t)(rowA0 + row) * K + k0 + kcs * 8, cA + c * 16);
            gload16(Bt + (size_t)(colB0 + row) * K + k0 + kcs * 8, cB + c * 16);
        }
        __syncthreads();
#pragma unroll
        for (int kk = 0; kk < 2; ++kk) {
            short8 af[4], bf[4];
#pragma unroll
            for (int m = 0; m < 4; ++m) {
                int row = WR * 64 + m * 16 + ln;
                af[m] = *(const short8*)(cA + row * 128 + ((kk * 64 + g * 16) ^ ((row & 7) << 4)));
            }
#pragma unroll
            for (int n = 0; n < 4; ++n) {
                int col = WC * 64 + n * 16 + ln;
                bf[n] = *(const short8*)(cB + col * 128 + ((kk * 64 + g * 16) ^ ((col & 7) << 4)));
            }
#pragma unroll
            for (int m = 0; m < 4; ++m)
#pragma unroll
                for (int n = 0; n < 4; ++n)
                    acc[m][n] = __builtin_amdgcn_mfma_f32_16x16x32_bf16(af[m], bf[n], acc[m][n], 0, 0, 0);
        }
    }

#pragma unroll
    for (int m = 0; m < 4; ++m) {
        const int rbase = rowA0 + WR * 64 + m * 16 + g * 4;
#pragma unroll
        for (int n = 0; n < 4; ++n) {
            const int col = colB0 + WC * 64 + n * 16 + ln;
            const float bcol = bias[col];
#pragma unroll
            for (int i = 0; i < 4; ++i) {
                const int row = rbase + i;
                const float v = acc[m][n][i] + bcol;
                if (blockIdx.z == 0) {
                    kfb[(size_t)row * N + col] = f2b(v);
                } else {
                    const int tb = row / TPAD, t = row - tb * TPAD;
                    const int h = col >> 6, d = col & 63;
                    vt[((size_t)(tb * NHEAD + h) * 64 + d) * 96 + t] = f2b(v);
                }
            }
        }
    }
}

// ---------------- 128x128 bf16 MFMA GEMM, BK=32 / 32 KiB LDS / 4 blocks per CU ----------------
// Occupancy lever within the VGPR bracket: 4 waves/block, wave tile 64x64
// (acc=64 + operands 32 + addr ~15 < 128-reg cap at 4 waves/SIMD). 4 resident
// blocks/CU: each block's vmcnt(0)+barrier drain overlaps 3 other blocks' MFMA.
// Round-8 low-barrier ledger: stage(t+1) into buf^1 (never live), ONE
// vmcnt(0)+barrier per tile. Bank swizzle (verified R12, 0 conflicts):
// unit ^= (row>>1)&3; per-thread-constant on reads: g ^ ((ln>>1)&3) -> 2-way (free).
template<int EPI>
__global__ __launch_bounds__(256, 4) void gemm128(
    const unsigned short* __restrict__ A, const unsigned short* __restrict__ Bt,
    const float* __restrict__ bias,
    unsigned short* __restrict__ outb, float* __restrict__ outf,
    int M, int N, int K,
    const unsigned short* __restrict__ xres, const float* __restrict__ gate,
    const float* __restrict__ byp, const unsigned short* __restrict__ yres,
    const float* __restrict__ alphaPtr, int gxM, int gyN)
{
    __shared__ unsigned short lds[2][2][4096];    // [buf][A/B][128*32] = 32 KiB
    const int tid = threadIdx.x;
    const int lane = tid & 63, w = tid >> 6;
    const int g = lane >> 4, ln = lane & 15;
    const int wr = w >> 1, wc = w & 1;

    // XCD-chunked bijective swizzle (gxM multiple of 8)
    int bm, bn;
    {
        const int L = (int)blockIdx.x;
        const int xcd = L & 7, j = L >> 3;
        const int rl = j / gyN;
        bn = j - rl * gyN;
        bm = xcd * (gxM >> 3) + rl;
    }
    const int rowA0 = bm * 128, colB0 = bn * 128;
    const int nt = K >> 5;                        // BK = 32

    auto stageA = [&](int t) {
        const int buf = t & 1;
#pragma unroll
        for (int r = 0; r < 2; ++r) {
            const int c = tid + r * 256;          // 0..511 16B slots (8 KB)
            const int row = c >> 2, kc = c & 3;
            const int kcs = kc ^ ((row >> 1) & 3);
            gload16(A + (size_t)(rowA0 + row) * K + (t << 5) + (kcs << 3),
                    (char*)&lds[buf][0][0] + c * 16);
        }
    };
    auto stageB = [&](int t) {
        const int buf = t & 1;
#pragma unroll
        for (int r = 0; r < 2; ++r) {
            const int c = tid + r * 256;
            const int row = c >> 2, kc = c & 3;
            const int kcs = kc ^ ((row >> 1) & 3);
            gload16(Bt + (size_t)(colB0 + row) * K + (t << 5) + (kcs << 3),
                    (char*)&lds[buf][1][0] + c * 16);
        }
    };

    f32x4 acc[4][4];
#pragma unroll
    for (int m = 0; m < 4; ++m)
#pragma unroll
        for (int n = 0; n < 4; ++n) acc[m][n] = (f32x4){0.f, 0.f, 0.f, 0.f};

    // prologue: stage tile 0; drain; barrier
    stageA(0); stageB(0);
    asm volatile("s_waitcnt vmcnt(0)" ::: "memory");
    __builtin_amdgcn_s_barrier();

    const int swz = (g ^ ((ln >> 1) & 3)) << 4;   // per-thread-constant unit swizzle
    const int arow = (wr * 64 + ln) * 64 + swz;   // + m*1024 (16 rows * 64B)
    const int brow = (wc * 64 + ln) * 64 + swz;   // + n*1024

    short8 af[4], bf[4];

#pragma unroll 2
    for (int t = 0; t < nt; ++t) {
        const char* lA = (const char*)&lds[t & 1][0][0];
        const char* lB = (const char*)&lds[t & 1][1][0];
        const bool pf = (t + 1 < nt);

#pragma unroll
        for (int m = 0; m < 4; ++m) af[m] = *(const short8*)(lA + arow + m * 1024);
#pragma unroll
        for (int n = 0; n < 4; ++n) bf[n] = *(const short8*)(lB + brow + n * 1024);
        if (pf) { stageA(t + 1); stageB(t + 1); }
        __builtin_amdgcn_s_setprio(1);
#pragma unroll
        for (int m = 0; m < 4; ++m)
#pragma unroll
            for (int n = 0; n < 4; ++n)
                acc[m][n] = __builtin_amdgcn_mfma_f32_16x16x32_bf16(af[m], bf[n], acc[m][n], 0, 0, 0);
        __builtin_amdgcn_s_setprio(0);

        // tile boundary: t+1 fully landed; all waves past tile-t reads
        if (pf) {
            asm volatile("s_waitcnt vmcnt(0)" ::: "memory");
            __builtin_amdgcn_s_barrier();
        }
    }

    // ---- epilogue ----
    const float alpha = (EPI == 1) ? *alphaPtr : 0.f;
#pragma unroll
    for (int m = 0; m < 4; ++m) {
        const int rbase = rowA0 + wr * 64 + m * 16 + g * 4;
#pragma unroll
        for (int n = 0; n < 4; ++n) {
            const int col = colB0 + wc * 64 + n * 16 + ln;
            const float bcol = bias[col];
#pragma unroll
            for (int i = 0; i < 4; ++i) {
                const int row = rbase + i;
                const float v = acc[m][n][i] + bcol;
                if (EPI == 0) {
                    outb[(size_t)row * N + col] = f2b(v);
                } else if (EPI == 1) {
                    float yp = b2f(xres[(size_t)row * N + col]) + alpha * gate[row] * byp[row] * v;
                    outb[(size_t)row * N + col] = f2b(yp);
                } else if (EPI == 2) {
                    const float u2 = 2.f * v * (0.7978845608f + 0.0356774081f * v * v);
                    const float tt = 1.f - 2.f / (__expf(u2) + 1.f);
                    outb[(size_t)row * N + col] = f2b(0.5f * v * (1.f + tt));
                } else {
                    outf[(size_t)row * N + col] = b2f(yres[(size_t)row * N + col]) + v;
                }
            }
        }
    }
}

// ---------------- fused attention (q-l2norm + allpad fused in) ----------------
// grid: (NTOK/16, B), block 256 = 4 waves; each wave: same 16 rows, heads {w, w+4}.
__global__ __launch_bounds__(256) void attn_kernel(
    const unsigned short* __restrict__ qn,   // [MROWS,512] raw q, bf16
    const unsigned short* __restrict__ kn,   // [B,80,512] l2-normed k, bf16
    const unsigned short* __restrict__ vt,   // [B*8][64][96] per-head V^T, bf16
    const float* __restrict__ padm,          // [B,80] 1.0 = pad
    const float* __restrict__ lscPtr,
    unsigned short* __restrict__ aligned,    // [MROWS,512] bf16
    float* __restrict__ bypass)              // [MROWS]
{
    const int b = blockIdx.y;
    const int n0 = blockIdx.x * 16;
    const int tid = threadIdx.x;
    const int w = tid >> 6, lane = tid & 63, g = lane >> 4, ln = lane & 15;
    __shared__ unsigned short s_p[4][16][104];
    __shared__ float s_conf[4][16];
    __shared__ float s_inv[16];

    // pad-mask of this lane's 5 t-columns (depends only on ln)
    float pm[5];
#pragma unroll
    for (int tt = 0; tt < 5; ++tt) {
        int t = ln + tt * 16;
        pm[tt] = (t < TTXT) ? padm[b * TPAD + t] : 1.f;
    }
    // all-pad check (fused allpad): min over t<77 of padm
    {
        float pmn = fminf(fminf(pm[0], pm[1]), fminf(fminf(pm[2], pm[3]), pm[4]));
        pmn = red16Min(pmn);
        if (pmn > 0.5f) {
            uint4 z = {0u, 0u, 0u, 0u};
#pragma unroll
            for (int j = 0; j < 4; ++j) {
                int id = tid + j * 256;
                int row = id >> 6, c8 = id & 63;
                *(uint4*)(aligned + ((size_t)(b * NTOK + n0 + row)) * 512 + c8 * 8) = z;
            }
            if (tid < 16) bypass[b * NTOK + n0 + tid] = 0.f;
            return;
        }
    }

    // ---- q-norm preamble: 16 rows x 512 ch; thread (r=tid>>4, seg=tid&15) ----
    {
        const int r = tid >> 4, seg = tid & 15;
        const unsigned short* qp = qn + ((size_t)(b * NTOK + n0 + r)) * 512 + seg * 32;
        float ss = 0.f;
#pragma unroll
        for (int j = 0; j < 4; ++j) {
            short8 u = *(const short8*)(qp + j * 8);
#pragma unroll
            for (int e = 0; e < 8; ++e) {
                float f = b2f(((const unsigned short*)&u)[e]);
                ss += f * f;
            }
        }
        ss = red16Add(ss);
        if (seg == 0) s_inv[r] = 1.f / fmaxf(sqrtf(ss), 1e-6f);
    }

    float lscale;
    {
        float ls = *lscPtr;
        ls = fminf(fmaxf(ls, -2.f), 2.f);
        lscale = __expf(ls) * 0.125f;
    }

    for (int j = g; j < 24; j += 4) s_p[w][ln][80 + j] = 0;
    __syncthreads();                               // s_inv ready

    float conf_acc[4] = {0.f, 0.f, 0.f, 0.f};
    const size_t qrow = ((size_t)(b * NTOK + n0 + ln)) * 512;

#pragma unroll
    for (int hh = 0; hh < 2; ++hh) {
        const int h = w + hh * 4;
        short8 a0 = *(const short8*)(qn + qrow + h * 64 + g * 8);
        short8 a1 = *(const short8*)(qn + qrow + h * 64 + 32 + g * 8);
        f32x4 sim[5];
#pragma unroll
        for (int tt = 0; tt < 5; ++tt) {
            const size_t kbase = ((size_t)(b * TPAD + tt * 16 + ln)) * 512 + h * 64;
            short8 b0 = *(const short8*)(kn + kbase + g * 8);
            short8 b1 = *(const short8*)(kn + kbase + 32 + g * 8);
            f32x4 c = (f32x4){0.f, 0.f, 0.f, 0.f};
            c = __builtin_amdgcn_mfma_f32_16x16x32_bf16(a0, b0, c, 0, 0, 0);
            c = __builtin_amdgcn_mfma_f32_16x16x32_bf16(a1, b1, c, 0, 0, 0);
            sim[tt] = c;
        }
#pragma unroll
        for (int i = 0; i < 4; ++i) {
            const float qs = lscale * s_inv[g * 4 + i];   // row = g*4+i (C/D layout)
            float v[5];
#pragma unroll
            for (int tt = 0; tt < 5; ++tt)
                v[tt] = (pm[tt] == 0.f) ? sim[tt][i] * qs : NEGINF;

            float lm = v[0];
#pragma unroll
            for (int tt = 1; tt < 5; ++tt) lm = fmaxf(lm, v[tt]);
            const float m1 = red16Max(lm);
            float lm2 = -3.0e38f;
#pragma unroll
            for (int tt = 0; tt < 5; ++tt) if (v[tt] < m1) lm2 = fmaxf(lm2, v[tt]);
            const float m2 = red16Max(lm2);
            float lm3 = -3.0e38f;
#pragma unroll
            for (int tt = 0; tt < 5; ++tt) if (v[tt] < m2) lm3 = fmaxf(lm3, v[tt]);
            const float m3 = red16Max(lm3);
            // packed count reduction: c1 + 128*c2 (both <= 80 < 128)
            float lc = 0.f;
#pragma unroll
            for (int tt = 0; tt < 5; ++tt) {
                if (v[tt] >= m1) lc += 1.f;
                if (v[tt] >= m2) lc += 128.f;
            }
            const float cpk = red16Add(lc);
            const float c2 = floorf(cpk * (1.f / 128.f));
            const float c1 = cpk - 128.f * c2;
            const float th = (c1 >= 3.f) ? m1 : ((c2 >= 3.f) ? m2 : m3);

            float p[5], lsum = 0.f, lcnt = 0.f;
#pragma unroll
            for (int tt = 0; tt < 5; ++tt) {
                float pv = (v[tt] >= th) ? __expf(v[tt] - m1) : 0.f;
                p[tt] = pv;
                lsum += pv;
                lcnt += (pv > 0.f) ? 1.f : 0.f;
            }
            const float psum = red16Add(lsum);
            const float pcnt = red16Add(lcnt);
            const float inv = 1.f / fmaxf(psum, 1e-20f);

            float lmaxp = 0.f, lent = 0.f;
#pragma unroll
            for (int tt = 0; tt < 5; ++tt) {
                float a = p[tt] * inv;
                p[tt] = a;
                lmaxp = fmaxf(lmaxp, a);
                if (a > 0.f) {
                    float pp = fmaxf(a, 1e-8f);
                    lent += -pp * __logf(pp);
                }
            }
            const float maxp = red16Max(lmaxp);
            float ent = red16Add(lent);
            ent += (77.f - pcnt) * 1.8420680744e-7f;
            const float teff = fmaxf(pcnt, 2.f);
            const float entropy = fmaxf(ent / __logf(teff), 0.f);
            const float confh = fminf(fmaxf(maxp * (1.f - entropy), 0.f), 1.f);
            conf_acc[i] += confh;

#pragma unroll
            for (int tt = 0; tt < 5; ++tt)
                s_p[w][g * 4 + i][ln + tt * 16] = f2b(p[tt]);
        }
        short8 af[3];
#pragma unroll
        for (int k = 0; k < 3; ++k)
            af[k] = *(const short8*)(&s_p[w][ln][k * 32 + g * 8]);
        const size_t vtb = ((size_t)(b * NHEAD + h)) * 64;
#pragma unroll
        for (int n = 0; n < 4; ++n) {
            f32x4 o = (f32x4){0.f, 0.f, 0.f, 0.f};
#pragma unroll
            for (int k = 0; k < 3; ++k) {
                short8 bf = *(const short8*)(vt + (vtb + n * 16 + ln) * 96 + k * 32 + g * 8);
                o = __builtin_amdgcn_mfma_f32_16x16x32_bf16(af[k], bf, o, 0, 0, 0);
            }
#pragma unroll
            for (int i = 0; i < 4; ++i)
                aligned[((size_t)(b * NTOK + n0 + g * 4 + i)) * 512 + h * 64 + n * 16 + ln] =
                    f2b(o[i]);
        }
    }

    if (ln == 0) {
#pragma unroll
        for (int i = 0; i < 4; ++i) s_conf[w][g * 4 + i] = conf_acc[i];
    }
    __syncthreads();
    if (tid < 16) {
        float c = (s_conf[0][tid] + s_conf[1][tid] + s_conf[2][tid] + s_conf[3][tid]) * 0.125f;
        bypass[b * NTOK + n0 + tid] = (c >= 0.35f) ? 1.f : 0.f;
    }
}

// ---------------- host side ----------------
extern "C" void kernel_launch(void* const* d_in, const int* in_sizes, int n_in,
                              void* d_out, int out_size, void* d_ws, size_t ws_size,
                              hipStream_t stream)
{
    (void)in_sizes; (void)n_in; (void)out_size;
    if (ws_size < WS_NEED) return;

    const float* visual = (const float*)d_in[0];
    const float* text   = (const float*)d_in[1];
    const float* ln1_g  = (const float*)d_in[2];
    const float* ln1_b  = (const float*)d_in[3];
    const float* ln2_g  = (const float*)d_in[4];
    const float* ln2_b  = (const float*)d_in[5];
    const float* Wq = (const float*)d_in[6];   const float* bq = (const float*)d_in[7];
    const float* Wk = (const float*)d_in[8];   const float* bk = (const float*)d_in[9];
    const float* Wv = (const float*)d_in[10];  const float* bv = (const float*)d_in[11];
    const float* Wo = (const float*)d_in[12];  const float* bo = (const float*)d_in[13];
    const float* Wg = (const float*)d_in[14];  const float* bg = (const float*)d_in[15];
    const float* W1 = (const float*)d_in[16];  const float* b1 = (const float*)d_in[17];
    const float* W2 = (const float*)d_in[18];  const float* b2 = (const float*)d_in[19];
    const float* lsc = (const float*)d_in[20];
    const float* alp = (const float*)d_in[21];

    char* ws = (char*)d_ws;
    unsigned short* WQT  = (unsigned short*)(ws + OFF_WQT);
    unsigned short* WKT  = (unsigned short*)(ws + OFF_WKT);
    unsigned short* WVT  = (unsigned short*)(ws + OFF_WVT);
    unsigned short* WOT  = (unsigned short*)(ws + OFF_WOT);
    unsigned short* W1T  = (unsigned short*)(ws + OFF_W1T);
    unsigned short* W2T  = (unsigned short*)(ws + OFF_W2T);
    unsigned short* TEXTB = (unsigned short*)(ws + OFF_TEXTB);
    unsigned short* KFB  = (unsigned short*)(ws + OFF_KFB);
    unsigned short* KNRM = (unsigned short*)(ws + OFF_KNRM);
    float* PADM = (float*)(ws + OFF_PADM);
    float* GATE = (float*)(ws + OFF_GATE);
    float* BYP  = (float*)(ws + OFF_BYP);
    unsigned short* XB   = (unsigned short*)(ws + OFF_XB);
    unsigned short* BUFB = (unsigned short*)(ws + OFF_BUFB);
    unsigned short* BUFC = (unsigned short*)(ws + OFF_BUFC);
    unsigned short* HBUF = (unsigned short*)(ws + OFF_H);
    unsigned short* VT   = (unsigned short*)(ws + OFF_VT);   // overlays HBUF
    float* out = (float*)d_out;

    // 1) prep: all weight transposes + text bf16/padmask + VT pad zero-fill
    prep_kernel<<<3728, 256, 0, stream>>>(Wq, Wk, Wv, Wo, W1, W2,
                                          WQT, WKT, WVT, WOT, W1T, W2T,
                                          text, TEXTB, PADM, VT);

    // 2) LN1 + gate
    ln1_gate_kernel<<<MROWS, 128, 0, stream>>>(visual, ln1_g, ln1_b, Wg, bg, XB, GATE);

    // 3) text K/V projections in one launch (V writes VT directly) + K l2norm
    gemm_kv<<<dim3(5, 4, 2), 256, 0, stream>>>(TEXTB, WKT, WVT, bk, bv, KFB, VT);
    l2norm_kernel<<<640, 128, 0, stream>>>(KFB, KNRM);

    // 4) Q projection (raw q -> BUFB; l2norm fused into attn)   [gxM=256, gyN=4]
    gemm128<0><<<dim3(256 * 4), 256, 0, stream>>>(XB, WQT, bq, BUFB, nullptr, MROWS, 512, 512,
                                                  nullptr, nullptr, nullptr, nullptr, nullptr,
                                                  256, 4);

    // 5) fused attention (q-norm + allpad inside) -> aligned (BUFC), bypass
    attn_kernel<<<dim3(NTOK / 16, BATCH), 256, 0, stream>>>(BUFB, KNRM, VT, PADM, lsc,
                                                            BUFC, BYP);

    // 6) Wo projection + gated residual -> ypre (BUFB)
    gemm128<1><<<dim3(256 * 4), 256, 0, stream>>>(BUFC, WOT, bo, BUFB, nullptr, MROWS, 512, 512,
                                                  XB, GATE, BYP, nullptr, alp, 256, 4);

    // 7) LN2 -> yb (XB)
    ln2_kernel<<<MROWS, 128, 0, stream>>>(BUFB, ln2_g, ln2_b, XB);

    // 8) MLP (HBUF reuses the VT region — VT is dead by now)
    gemm128<2><<<dim3(256 * 16), 256, 0, stream>>>(XB, W1T, b1, HBUF, nullptr, MROWS, HID, 512,
                                                   nullptr, nullptr, nullptr, nullptr, nullptr,
                                                   256, 16);
    gemm128<3><<<dim3(256 * 4), 256, 0, stream>>>(HBUF, W2T, b2, nullptr, out, MROWS, 512, HID,
                                                  nullptr, nullptr, nullptr, XB, nullptr,
                                                  256, 4);
}

// Round 14
// 372.244 us; speedup vs baseline: 5.8112x; 1.0358x over previous
//
#include <hip/hip_runtime.h>
#include <stdint.h>

// ---------------- problem constants ----------------
#define BATCH 8
#define NTOK 4096          // 64*64
#define CDIM 512
#define TTXT 77
#define TPAD 80
#define NHEAD 8
#define HDIM 64
#define HID 2048           // 4*C
#define MROWS 32768        // B*NTOK
#define NEGINF (-1e30f)

typedef __attribute__((ext_vector_type(8))) short short8;
typedef __attribute__((ext_vector_type(4))) float f32x4;

__device__ __forceinline__ float b2f(unsigned short u) {
    union { unsigned int i; float f; } x; x.i = ((unsigned int)u) << 16; return x.f;
}
__device__ __forceinline__ unsigned short f2b(float f) {
    union { float f; unsigned int i; } x; x.f = f;
    unsigned int i = x.i;
    return (unsigned short)((i + 0x7fffu + ((i >> 16) & 1u)) >> 16);
}

// async global->LDS, 16B per lane; LDS dest must be linear in lane order
__device__ __forceinline__ void gload16(const void* g, void* l) {
    __builtin_amdgcn_global_load_lds(
        (const __attribute__((address_space(1))) unsigned int*)g,
        (__attribute__((address_space(3))) unsigned int*)l, 16, 0, 0);
}

// ---------------- workspace layout (bytes) ----------------
#define OFF_WQT   ((size_t)0)
#define OFF_WKT   (OFF_WQT + 512*512*2)
#define OFF_WVT   (OFF_WKT + 512*512*2)
#define OFF_WOT   (OFF_WVT + 512*512*2)
#define OFF_W1T   (OFF_WOT + 512*512*2)
#define OFF_W2T   (OFF_W1T + (size_t)2048*512*2)
#define OFF_TEXTB (OFF_W2T + (size_t)512*2048*2)
#define OFF_KFB   (OFF_TEXTB + (size_t)640*512*2)
#define OFF_KNRM  (OFF_KFB + (size_t)640*512*2)
#define OFF_VPAD  (OFF_KNRM + (size_t)640*512*2)
#define OFF_PADM  (OFF_VPAD + (size_t)640*512*2)
#define OFF_ALLP  (OFF_PADM + 2560)
#define OFF_GATE  (OFF_ALLP + 256)
#define OFF_BYP   (OFF_GATE + (size_t)MROWS*4)
#define OFF_XB    (OFF_BYP + (size_t)MROWS*4)
#define OFF_BUFB  (OFF_XB + (size_t)MROWS*CDIM*2)
#define OFF_BUFC  (OFF_BUFB + (size_t)MROWS*CDIM*2)
#define OFF_H     (OFF_BUFC + (size_t)MROWS*CDIM*2)
#define WS_NEED   (OFF_H + (size_t)MROWS*HID*2)
// VT overlays HBUF (dead until the MLP phase): [B*NHEAD][64][96] bf16 = 768 KiB
#define OFF_VT    OFF_H

// ---------------- small helpers ----------------
__device__ __forceinline__ float waveReduceAdd(float v) {
#pragma unroll
    for (int m = 1; m < 64; m <<= 1) v += __shfl_xor(v, m);
    return v;
}
__device__ __forceinline__ float red16Max(float v) {
#pragma unroll
    for (int m = 1; m < 16; m <<= 1) v = fmaxf(v, __shfl_xor(v, m));
    return v;
}
__device__ __forceinline__ float red16Add(float v) {
#pragma unroll
    for (int m = 1; m < 16; m <<= 1) v += __shfl_xor(v, m);
    return v;
}
__device__ __forceinline__ float red16Min(float v) {
#pragma unroll
    for (int m = 1; m < 16; m <<= 1) v = fminf(v, __shfl_xor(v, m));
    return v;
}

// ---------------- prep mega-kernel ----------------
__global__ __launch_bounds__(256) void prep_kernel(
    const float* __restrict__ Wq, const float* __restrict__ Wk,
    const float* __restrict__ Wv, const float* __restrict__ Wo,
    const float* __restrict__ W1, const float* __restrict__ W2,
    unsigned short* __restrict__ WQT, unsigned short* __restrict__ WKT,
    unsigned short* __restrict__ WVT, unsigned short* __restrict__ WOT,
    unsigned short* __restrict__ W1T, unsigned short* __restrict__ W2T,
    const float* __restrict__ text, unsigned short* __restrict__ textb,
    float* __restrict__ padm, unsigned short* __restrict__ vt)
{
    __shared__ float tile[32][33];
    __shared__ float sred[4];
    int b = blockIdx.x;
    const int tid = threadIdx.x;

    if (b >= 3712) {
        const int i = b - 3712;
        const int bh = i * 4 + (tid >> 6), d = tid & 63;
        uint4 z = {0u, 0u, 0u, 0u};
        uint4* p = (uint4*)(vt + ((size_t)bh * 64 + d) * 96 + 80);
        p[0] = z; p[1] = z;
        return;
    }
    if (b >= 3072) {
        const int r = b - 3072;                 // 0..639
        const int tb = r / TPAD, t = r % TPAD;
        if (t < TTXT) {
            const float2 v = ((const float2*)(text + ((size_t)(tb * TTXT + t)) * 512))[tid];
            float a = fabsf(v.x) + fabsf(v.y);
            a = waveReduceAdd(a);
            if ((tid & 63) == 0) sred[tid >> 6] = a;
            __syncthreads();
            const float asum = sred[0] + sred[1] + sred[2] + sred[3];
            ushort2 o; o.x = f2b(v.x); o.y = f2b(v.y);
            ((ushort2*)(textb + (size_t)r * 512))[tid] = o;
            if (tid == 0) padm[r] = (asum <= 1e-6f) ? 1.f : 0.f;
        } else {
            ushort2 z; z.x = 0; z.y = 0;
            ((ushort2*)(textb + (size_t)r * 512))[tid] = z;
            if (tid == 0) padm[r] = 1.f;
        }
        return;
    }

    const float* src; unsigned short* dst; int R, C, cx, ry;
    if (b < 1024)       { src = W1; dst = W1T; R = 512;  C = 2048; cx = b & 63; ry = b >> 6; }
    else if (b < 2048)  { b -= 1024; src = W2; dst = W2T; R = 2048; C = 512; cx = b & 15; ry = b >> 4; }
    else {
        b -= 2048; const int which = b >> 8; b &= 255;
        R = 512; C = 512; cx = b & 15; ry = b >> 4;
        src = (which == 0) ? Wq : (which == 1) ? Wk : (which == 2) ? Wv : Wo;
        dst = (which == 0) ? WQT : (which == 1) ? WKT : (which == 2) ? WVT : WOT;
    }
    const int tx = threadIdx.x & 31, ty = threadIdx.x >> 5;  // ty 0..7
    const int c0 = cx * 32, r0 = ry * 32;
#pragma unroll
    for (int i = 0; i < 32; i += 8)
        tile[ty + i][tx] = src[(size_t)(r0 + ty + i) * C + c0 + tx];
    __syncthreads();
#pragma unroll
    for (int i = 0; i < 32; i += 8)
        dst[(size_t)(c0 + ty + i) * R + r0 + tx] = f2b(tile[tx][ty + i]);
}

// ---------------- LN1 + gate ----------------
__global__ __launch_bounds__(128) void ln1_gate_kernel(
    const float* __restrict__ vin, const float* __restrict__ g1, const float* __restrict__ b1v,
    const float* __restrict__ Wg, const float* __restrict__ bg,
    unsigned short* __restrict__ xb, float* __restrict__ gate)
{
    __shared__ float sred[4];
    const int row = blockIdx.x, tid = threadIdx.x;
    const float4 v = *(const float4*)(vin + (size_t)row * 512 + tid * 4);
    float s = v.x + v.y + v.z + v.w;
    float s2 = v.x * v.x + v.y * v.y + v.z * v.z + v.w * v.w;
    s = waveReduceAdd(s); s2 = waveReduceAdd(s2);
    if ((tid & 63) == 0) { sred[tid >> 6] = s; sred[2 + (tid >> 6)] = s2; }
    __syncthreads();
    s = sred[0] + sred[1]; s2 = sred[2] + sred[3];
    const float mu = s * (1.f / 512.f);
    float var = s2 * (1.f / 512.f) - mu * mu;
    const float rs = rsqrtf(fmaxf(var, 0.f) + 1e-5f);
    const float4 gg = *(const float4*)(g1 + tid * 4);
    const float4 bb = *(const float4*)(b1v + tid * 4);
    const float x0 = (v.x - mu) * rs * gg.x + bb.x;
    const float x1 = (v.y - mu) * rs * gg.y + bb.y;
    const float x2 = (v.z - mu) * rs * gg.z + bb.z;
    const float x3 = (v.w - mu) * rs * gg.w + bb.w;
    ushort4 o; o.x = f2b(x0); o.y = f2b(x1); o.z = f2b(x2); o.w = f2b(x3);
    *(ushort4*)(xb + (size_t)row * 512 + tid * 4) = o;
    const float4 wg = *(const float4*)(Wg + tid * 4);
    float gp = x0 * wg.x + x1 * wg.y + x2 * wg.z + x3 * wg.w;
    gp = waveReduceAdd(gp);
    __syncthreads();
    if ((tid & 63) == 0) sred[tid >> 6] = gp;
    __syncthreads();
    if (tid == 0) {
        float z = sred[0] + sred[1] + bg[0];
        gate[row] = 1.f / (1.f + __expf(-z));
    }
}

// ---------------- LN2 ----------------
__global__ __launch_bounds__(128) void ln2_kernel(
    const unsigned short* __restrict__ yin, const float* __restrict__ g2, const float* __restrict__ b2v,
    unsigned short* __restrict__ yb)
{
    __shared__ float sred[4];
    const int row = blockIdx.x, tid = threadIdx.x;
    ushort4 u = *(const ushort4*)(yin + (size_t)row * 512 + tid * 4);
    float v0 = b2f(u.x), v1 = b2f(u.y), v2 = b2f(u.z), v3 = b2f(u.w);
    float s = v0 + v1 + v2 + v3;
    float s2 = v0 * v0 + v1 * v1 + v2 * v2 + v3 * v3;
    s = waveReduceAdd(s); s2 = waveReduceAdd(s2);
    if ((tid & 63) == 0) { sred[tid >> 6] = s; sred[2 + (tid >> 6)] = s2; }
    __syncthreads();
    s = sred[0] + sred[1]; s2 = sred[2] + sred[3];
    const float mu = s * (1.f / 512.f);
    float var = s2 * (1.f / 512.f) - mu * mu;
    const float rs = rsqrtf(fmaxf(var, 0.f) + 1e-5f);
    const float4 gg = *(const float4*)(g2 + tid * 4);
    const float4 bb = *(const float4*)(b2v + tid * 4);
    ushort4 o;
    o.x = f2b((v0 - mu) * rs * gg.x + bb.x);
    o.y = f2b((v1 - mu) * rs * gg.y + bb.y);
    o.z = f2b((v2 - mu) * rs * gg.z + bb.z);
    o.w = f2b((v3 - mu) * rs * gg.w + bb.w);
    *(ushort4*)(yb + (size_t)row * 512 + tid * 4) = o;
}

// ---------------- row l2-normalize bf16 -> bf16 (K only, 640 rows) ----------------
__global__ __launch_bounds__(128) void l2norm_kernel(
    const unsigned short* __restrict__ in, unsigned short* __restrict__ out)
{
    __shared__ float sred[2];
    const int row = blockIdx.x, tid = threadIdx.x;
    ushort4 u = *(const ushort4*)(in + (size_t)row * 512 + tid * 4);
    float v0 = b2f(u.x), v1 = b2f(u.y), v2 = b2f(u.z), v3 = b2f(u.w);
    float ss = v0 * v0 + v1 * v1 + v2 * v2 + v3 * v3;
    ss = waveReduceAdd(ss);
    if ((tid & 63) == 0) sred[tid >> 6] = ss;
    __syncthreads();
    ss = sred[0] + sred[1];
    const float inv = 1.f / fmaxf(sqrtf(ss), 1e-6f);
    ushort4 o;
    o.x = f2b(v0 * inv); o.y = f2b(v1 * inv); o.z = f2b(v2 * inv); o.w = f2b(v3 * inv);
    *(ushort4*)(out + (size_t)row * 512 + tid * 4) = o;
}

// ---------------- merged text K/V GEMM (128x128, M=640) ----------------
__global__ __launch_bounds__(256) void gemm_kv(
    const unsigned short* __restrict__ A,
    const unsigned short* __restrict__ BtK, const unsigned short* __restrict__ BtV,
    const float* __restrict__ bk, const float* __restrict__ bv,
    unsigned short* __restrict__ kfb, unsigned short* __restrict__ vt)
{
    const int K = 512, N = 512;
    const unsigned short* Bt = blockIdx.z ? BtV : BtK;
    const float* bias = blockIdx.z ? bv : bk;
    __shared__ unsigned short sA[128 * 64];
    __shared__ unsigned short sB[128 * 64];
    char* cA = (char*)sA;
    char* cB = (char*)sB;
    const int tid = threadIdx.x;
    const int lane = tid & 63, w = tid >> 6;
    const int g = lane >> 4, ln = lane & 15;
    const int WR = w >> 1, WC = w & 1;
    const int rowA0 = blockIdx.x * 128, colB0 = blockIdx.y * 128;

    f32x4 acc[4][4];
#pragma unroll
    for (int m = 0; m < 4; ++m)
#pragma unroll
        for (int n = 0; n < 4; ++n) acc[m][n] = (f32x4){0.f, 0.f, 0.f, 0.f};

    for (int k0 = 0; k0 < K; k0 += 64) {
        __syncthreads();
#pragma unroll
        for (int i = 0; i < 4; ++i) {
            int c = tid + i * 256;
            int row = c >> 3, kc = c & 7;
            int kcs = kc ^ (row & 7);
            gload16(A + (size_t)(rowA0 + row) * K + k0 + kcs * 8, cA + c * 16);
            gload16(Bt + (size_t)(colB0 + row) * K + k0 + kcs * 8, cB + c * 16);
        }
        __syncthreads();
#pragma unroll
        for (int kk = 0; kk < 2; ++kk) {
            short8 af[4], bf[4];
#pragma unroll
            for (int m = 0; m < 4; ++m) {
                int row = WR * 64 + m * 16 + ln;
                af[m] = *(const short8*)(cA + row * 128 + ((kk * 64 + g * 16) ^ ((row & 7) << 4)));
            }
#pragma unroll
            for (int n = 0; n < 4; ++n) {
                int col = WC * 64 + n * 16 + ln;
                bf[n] = *(const short8*)(cB + col * 128 + ((kk * 64 + g * 16) ^ ((col & 7) << 4)));
            }
#pragma unroll
            for (int m = 0; m < 4; ++m)
#pragma unroll
                for (int n = 0; n < 4; ++n)
                    acc[m][n] = __builtin_amdgcn_mfma_f32_16x16x32_bf16(af[m], bf[n], acc[m][n], 0, 0, 0);
        }
    }

#pragma unroll
    for (int m = 0; m < 4; ++m) {
        const int rbase = rowA0 + WR * 64 + m * 16 + g * 4;
#pragma unroll
        for (int n = 0; n < 4; ++n) {
            const int col = colB0 + WC * 64 + n * 16 + ln;
            const float bcol = bias[col];
#pragma unroll
            for (int i = 0; i < 4; ++i) {
                const int row = rbase + i;
                const float v = acc[m][n][i] + bcol;
                if (blockIdx.z == 0) {
                    kfb[(size_t)row * N + col] = f2b(v);
                } else {
                    const int tb = row / TPAD, t = row - tb * TPAD;
                    const int h = col >> 6, d = col & 63;
                    vt[((size_t)(tb * NHEAD + h) * 64 + d) * 96 + t] = f2b(v);
                }
            }
        }
    }
}

// ---------------- GEMM epilogue (shared by both 256^2 kernels) ----------------
template<int EPI>
__device__ __forceinline__ void gemm_epilogue(
    f32x4 (&acc)[8][4], int rowA0, int colB0, int wr, int wc, int g, int ln,
    const float* __restrict__ bias,
    unsigned short* __restrict__ outb, float* __restrict__ outf, int N,
    const unsigned short* __restrict__ xres, const float* __restrict__ gate,
    const float* __restrict__ byp, const unsigned short* __restrict__ yres,
    const float* __restrict__ alphaPtr)
{
    const float alpha = (EPI == 1) ? *alphaPtr : 0.f;
#pragma unroll
    for (int m = 0; m < 8; ++m) {
        const int rbase = rowA0 + wr * 128 + m * 16 + g * 4;
#pragma unroll
        for (int n = 0; n < 4; ++n) {
            const int col = colB0 + wc * 64 + n * 16 + ln;
            const float bcol = bias[col];
#pragma unroll
            for (int i = 0; i < 4; ++i) {
                const int row = rbase + i;
                const float v = acc[m][n][i] + bcol;
                if (EPI == 0) {
                    outb[(size_t)row * N + col] = f2b(v);
                } else if (EPI == 1) {
                    float yp = b2f(xres[(size_t)row * N + col]) + alpha * gate[row] * byp[row] * v;
                    outb[(size_t)row * N + col] = f2b(yp);
                } else if (EPI == 2) {
                    const float u2 = 2.f * v * (0.7978845608f + 0.0356774081f * v * v);
                    const float tt = 1.f - 2.f / (__expf(u2) + 1.f);
                    outb[(size_t)row * N + col] = f2b(0.5f * v * (1.f + tt));
                } else {
                    outf[(size_t)row * N + col] = b2f(yres[(size_t)row * N + col]) + v;
                }
            }
        }
    }
}

// ---------------- 256x256 bf16 MFMA GEMM, R10 best-known (Q / Wo) ----------------
#define SEAM() __builtin_amdgcn_sched_barrier(0x106)

template<int EPI>
__global__ __launch_bounds__(512, 2) void gemm256(
    const unsigned short* __restrict__ A, const unsigned short* __restrict__ Bt,
    const float* __restrict__ bias,
    unsigned short* __restrict__ outb, float* __restrict__ outf,
    int M, int N, int K,
    const unsigned short* __restrict__ xres, const float* __restrict__ gate,
    const float* __restrict__ byp, const unsigned short* __restrict__ yres,
    const float* __restrict__ alphaPtr, int gxM, int gyN)
{
    __shared__ unsigned short lds[2][2][16384];   // [buf][A/B][256*64] = 128 KiB
    const int tid = threadIdx.x;
    const int lane = tid & 63, w = tid >> 6;
    const int g = lane >> 4, ln = lane & 15;
    const int wr = w >> 2, wc = w & 3;

    int bm, bn;
    {
        const int L = (int)blockIdx.x;
        const int xcd = L & 7, j = L >> 3;
        const int rl = j / gyN;
        bn = j - rl * gyN;
        bm = xcd * (gxM >> 3) + rl;
    }
    const int rowA0 = bm * 256, colB0 = bn * 256;
    const int nt = K >> 6;

    auto stageA = [&](int t, int mh) {
        const int buf = t & 1;
#pragma unroll
        for (int r = 0; r < 2; ++r) {
            const int c = tid + r * 512;
            const int prl = c >> 3, kc = c & 7;
            const int grow = rowA0 + ((prl >> 6) << 7) + (mh << 6) + (prl & 63);
            gload16(A + (size_t)grow * K + (t << 6) + ((kc ^ (prl & 7)) << 3),
                    (char*)&lds[buf][0][mh * 8192] + c * 16);
        }
    };
    auto stageB = [&](int t, int nh) {
        const int buf = t & 1;
#pragma unroll
        for (int r = 0; r < 2; ++r) {
            const int c = tid + r * 512;
            const int prl = c >> 3, kc = c & 7;
            const int gcol = colB0 + ((prl >> 5) << 6) + (nh << 5) + (prl & 31);
            gload16(Bt + (size_t)gcol * K + (t << 6) + ((kc ^ (prl & 7)) << 3),
                    (char*)&lds[buf][1][nh * 8192] + c * 16);
        }
    };

    f32x4 acc[8][4];
#pragma unroll
    for (int m = 0; m < 8; ++m)
#pragma unroll
        for (int n = 0; n < 4; ++n) acc[m][n] = (f32x4){0.f, 0.f, 0.f, 0.f};

    stageA(0, 0); stageA(0, 1); stageB(0, 0); stageB(0, 1);
    asm volatile("s_waitcnt vmcnt(0)" ::: "memory");
    __builtin_amdgcn_s_barrier();

    const int sw  = (ln & 7) << 4;
    const int kb0 = (g * 16) ^ sw;
    const int kb1 = (64 + g * 16) ^ sw;
    const int arow = (wr * 64 + ln) * 128;
    const int brow = (wc * 32 + ln) * 128;

    short8 afr[4][2], bfr[4][2];

#pragma unroll 2
    for (int t = 0; t < nt; ++t) {
        const char* lA = (const char*)&lds[t & 1][0][0];
        const char* lB = (const char*)&lds[t & 1][1][0];
        const bool pf = (t + 1 < nt);

        // q0
#pragma unroll
        for (int m = 0; m < 4; ++m) {
            afr[m][0] = *(const short8*)(lA + arow + m * 2048 + kb0);
            afr[m][1] = *(const short8*)(lA + arow + m * 2048 + kb1);
        }
#pragma unroll
        for (int n = 0; n < 2; ++n) {
            bfr[n][0] = *(const short8*)(lB + brow + n * 2048 + kb0);
            bfr[n][1] = *(const short8*)(lB + brow + n * 2048 + kb1);
        }
        if (pf) { stageA(t + 1, 0); stageA(t + 1, 1); }
        __builtin_amdgcn_s_setprio(1);
#pragma unroll
        for (int m = 0; m < 4; ++m)
#pragma unroll
            for (int n = 0; n < 2; ++n) {
                acc[m][n] = __builtin_amdgcn_mfma_f32_16x16x32_bf16(afr[m][0], bfr[n][0], acc[m][n], 0, 0, 0);
                acc[m][n] = __builtin_amdgcn_mfma_f32_16x16x32_bf16(afr[m][1], bfr[n][1], acc[m][n], 0, 0, 0);
            }
        __builtin_amdgcn_s_setprio(0);
        SEAM();

        // q1
#pragma unroll
        for (int n = 2; n < 4; ++n) {
            bfr[n][0] = *(const short8*)(lB + brow + (n & 1) * 2048 + 16384 + kb0);
            bfr[n][1] = *(const short8*)(lB + brow + (n & 1) * 2048 + 16384 + kb1);
        }
        if (pf) { stageB(t + 1, 0); stageB(t + 1, 1); }
        __builtin_amdgcn_s_setprio(1);
#pragma unroll
        for (int m = 0; m < 4; ++m)
#pragma unroll
            for (int n = 2; n < 4; ++n) {
                acc[m][n] = __builtin_amdgcn_mfma_f32_16x16x32_bf16(afr[m][0], bfr[n][0], acc[m][n], 0, 0, 0);
                acc[m][n] = __builtin_amdgcn_mfma_f32_16x16x32_bf16(afr[m][1], bfr[n][1], acc[m][n], 0, 0, 0);
            }
        __builtin_amdgcn_s_setprio(0);
        SEAM();

        // q2
#pragma unroll
        for (int m = 0; m < 4; ++m) {
            afr[m][0] = *(const short8*)(lA + arow + m * 2048 + 16384 + kb0);
            afr[m][1] = *(const short8*)(lA + arow + m * 2048 + 16384 + kb1);
        }
        __builtin_amdgcn_s_setprio(1);
#pragma unroll
        for (int m = 0; m < 4; ++m)
#pragma unroll
            for (int n = 0; n < 2; ++n) {
                acc[m + 4][n] = __builtin_amdgcn_mfma_f32_16x16x32_bf16(afr[m][0], bfr[n][0], acc[m + 4][n], 0, 0, 0);
                acc[m + 4][n] = __builtin_amdgcn_mfma_f32_16x16x32_bf16(afr[m][1], bfr[n][1], acc[m + 4][n], 0, 0, 0);
            }
        __builtin_amdgcn_s_setprio(0);
        SEAM();

        // q3
        __builtin_amdgcn_s_setprio(1);
#pragma unroll
        for (int m = 0; m < 4; ++m)
#pragma unroll
            for (int n = 2; n < 4; ++n) {
                acc[m + 4][n] = __builtin_amdgcn_mfma_f32_16x16x32_bf16(afr[m][0], bfr[n][0], acc[m + 4][n], 0, 0, 0);
                acc[m + 4][n] = __builtin_amdgcn_mfma_f32_16x16x32_bf16(afr[m][1], bfr[n][1], acc[m + 4][n], 0, 0, 0);
            }
        __builtin_amdgcn_s_setprio(0);

        if (pf) {
            asm volatile("s_waitcnt vmcnt(0)" ::: "memory");
            __builtin_amdgcn_s_barrier();
        }
    }

    gemm_epilogue<EPI>(acc, rowA0, colB0, wr, wc, g, ln, bias, outb, outf, N,
                       xres, gate, byp, yres, alphaPtr);
}
#undef SEAM

// ---------------- 256x256 bf16 MFMA GEMM, TRI-BUFFER counted-vmcnt (W1 / W2) ----------------
// T4 experiment: BK=32, 3 LDS buffers (96 KiB), stage tile t+2 during tile t,
// boundary waits vmcnt(4) -> tile t+1's 4 stage-units retired, t+2's stay in
// flight ACROSS the barrier (a full tile of MFMA covers t+1's memory latency).
// vmcnt(0) only at t==nt-2. Ledger: buf (t+2)%3 == (t-1)%3, last read before the
// (t-1)->t boundary barrier — 1-barrier separation (same as the race-clean R8
// ledger). Swizzle: BK-32 involution (absmax-verified R12/R13, measured 0
// bank conflicts): unit ^= (row>>1)&3; read side per-thread-constant g^((ln>>1)&3).
template<int EPI>
__global__ __launch_bounds__(512, 2) void gemm256t(
    const unsigned short* __restrict__ A, const unsigned short* __restrict__ Bt,
    const float* __restrict__ bias,
    unsigned short* __restrict__ outb, float* __restrict__ outf,
    int M, int N, int K,
    const unsigned short* __restrict__ xres, const float* __restrict__ gate,
    const float* __restrict__ byp, const unsigned short* __restrict__ yres,
    const float* __restrict__ alphaPtr, int gxM, int gyN)
{
    __shared__ unsigned short lds[3][2][8192];    // [buf][A/B][256*32] = 96 KiB
    const int tid = threadIdx.x;
    const int lane = tid & 63, w = tid >> 6;
    const int g = lane >> 4, ln = lane & 15;
    const int wr = w >> 2, wc = w & 3;

    int bm, bn;
    {
        const int L = (int)blockIdx.x;
        const int xcd = L & 7, j = L >> 3;
        const int rl = j / gyN;
        bn = j - rl * gyN;
        bm = xcd * (gxM >> 3) + rl;
    }
    const int rowA0 = bm * 256, colB0 = bn * 256;
    const int nt = K >> 5;                        // BK = 32 (nt >= 16 for all callers)

    // one stage call = 2 gload16 wave-instructions; A+B = 4 per tile
    auto stageA = [&](int t, int buf) {
#pragma unroll
        for (int r = 0; r < 2; ++r) {
            const int c = tid + r * 512;          // 0..1023 16B slots (16 KB)
            const int row = c >> 2, kc = c & 3;
            const int kcs = kc ^ ((row >> 1) & 3);
            gload16(A + (size_t)(rowA0 + row) * K + (t << 5) + (kcs << 3),
                    (char*)&lds[buf][0][0] + c * 16);
        }
    };
    auto stageB = [&](int t, int buf) {
#pragma unroll
        for (int r = 0; r < 2; ++r) {
            const int c = tid + r * 512;
            const int row = c >> 2, kc = c & 3;
            const int kcs = kc ^ ((row >> 1) & 3);
            gload16(Bt + (size_t)(colB0 + row) * K + (t << 5) + (kcs << 3),
                    (char*)&lds[buf][1][0] + c * 16);
        }
    };

    f32x4 acc[8][4];
#pragma unroll
    for (int m = 0; m < 8; ++m)
#pragma unroll
        for (int n = 0; n < 4; ++n) acc[m][n] = (f32x4){0.f, 0.f, 0.f, 0.f};

    // prologue: stage t0->buf0, t1->buf1; retire t0 (t1 stays in flight); barrier
    stageA(0, 0); stageB(0, 0);
    stageA(1, 1); stageB(1, 1);
    asm volatile("s_waitcnt vmcnt(4)" ::: "memory");
    __builtin_amdgcn_s_barrier();

    const int swz = (g ^ ((ln >> 1) & 3)) << 4;   // per-thread-constant unit swizzle
    const int arow = (wr * 128 + ln) * 64 + swz;  // + m*1024 (16 rows * 64B)
    const int brow = (wc * 64 + ln) * 64 + swz;   // + n*1024

    short8 af[8], bf[4];
    int cb = 0;                                   // current buffer = t % 3

    for (int t = 0; t < nt; ++t) {
        const char* lA = (const char*)&lds[cb][0][0];
        const char* lB = (const char*)&lds[cb][1][0];

        // 12 ds_reads for this tile
#pragma unroll
        for (int m = 0; m < 8; ++m) af[m] = *(const short8*)(lA + arow + m * 1024);
#pragma unroll
        for (int n = 0; n < 4; ++n) bf[n] = *(const short8*)(lB + brow + n * 1024);

        // stage tile t+2 into buf (t+2)%3 == (cb+2)%3 (last read at tile t-1)
        if (t + 2 < nt) {
            int nb = cb + 2; if (nb >= 3) nb -= 3;
            stageA(t + 2, nb); stageB(t + 2, nb);
        }

        __builtin_amdgcn_s_setprio(1);
#pragma unroll
        for (int m = 0; m < 8; ++m)
#pragma unroll
            for (int n = 0; n < 4; ++n)
                acc[m][n] = __builtin_amdgcn_mfma_f32_16x16x32_bf16(af[m], bf[n], acc[m][n], 0, 0, 0);
        __builtin_amdgcn_s_setprio(0);

        // boundary: retire t+1's 4 units; t+2's 4 remain in flight across the barrier
        if (t + 1 < nt) {
            if (t + 2 < nt) { asm volatile("s_waitcnt vmcnt(4)" ::: "memory"); }
            else            { asm volatile("s_waitcnt vmcnt(0)" ::: "memory"); }
            __builtin_amdgcn_s_barrier();
        }
        cb = (cb == 2) ? 0 : cb + 1;
    }

    gemm_epilogue<EPI>(acc, rowA0, colB0, wr, wc, g, ln, bias, outb, outf, N,
                       xres, gate, byp, yres, alphaPtr);
}

// ---------------- fused attention (q-l2norm + allpad fused in) ----------------
__global__ __launch_bounds__(256) void attn_kernel(
    const unsigned short* __restrict__ qn,   // [MROWS,512] raw q, bf16
    const unsigned short* __restrict__ kn,   // [B,80,512] l2-normed k, bf16
    const unsigned short* __restrict__ vt,   // [B*8][64][96] per-head V^T, bf16
    const float* __restrict__ padm,          // [B,80] 1.0 = pad
    const float* __restrict__ lscPtr,
    unsigned short* __restrict__ aligned,    // [MROWS,512] bf16
    float* __restrict__ bypass)              // [MROWS]
{
    const int b = blockIdx.y;
    const int n0 = blockIdx.x * 16;
    const int tid = threadIdx.x;
    const int w = tid >> 6, lane = tid & 63, g = lane >> 4, ln = lane & 15;
    __shared__ unsigned short s_p[4][16][104];
    __shared__ float s_conf[4][16];
    __shared__ float s_inv[16];

    float pm[5];
#pragma unroll
    for (int tt = 0; tt < 5; ++tt) {
        int t = ln + tt * 16;
        pm[tt] = (t < TTXT) ? padm[b * TPAD + t] : 1.f;
    }
    {
        float pmn = fminf(fminf(pm[0], pm[1]), fminf(fminf(pm[2], pm[3]), pm[4]));
        pmn = red16Min(pmn);
        if (pmn > 0.5f) {
            uint4 z = {0u, 0u, 0u, 0u};
#pragma unroll
            for (int j = 0; j < 4; ++j) {
                int id = tid + j * 256;
                int row = id >> 6, c8 = id & 63;
                *(uint4*)(aligned + ((size_t)(b * NTOK + n0 + row)) * 512 + c8 * 8) = z;
            }
            if (tid < 16) bypass[b * NTOK + n0 + tid] = 0.f;
            return;
        }
    }

    {
        const int r = tid >> 4, seg = tid & 15;
        const unsigned short* qp = qn + ((size_t)(b * NTOK + n0 + r)) * 512 + seg * 32;
        float ss = 0.f;
#pragma unroll
        for (int j = 0; j < 4; ++j) {
            short8 u = *(const short8*)(qp + j * 8);
#pragma unroll
            for (int e = 0; e < 8; ++e) {
                float f = b2f(((const unsigned short*)&u)[e]);
                ss += f * f;
            }
        }
        ss = red16Add(ss);
        if (seg == 0) s_inv[r] = 1.f / fmaxf(sqrtf(ss), 1e-6f);
    }

    float lscale;
    {
        float ls = *lscPtr;
        ls = fminf(fmaxf(ls, -2.f), 2.f);
        lscale = __expf(ls) * 0.125f;
    }

    for (int j = g; j < 24; j += 4) s_p[w][ln][80 + j] = 0;
    __syncthreads();                               // s_inv ready

    float conf_acc[4] = {0.f, 0.f, 0.f, 0.f};
    const size_t qrow = ((size_t)(b * NTOK + n0 + ln)) * 512;

#pragma unroll
    for (int hh = 0; hh < 2; ++hh) {
        const int h = w + hh * 4;
        short8 a0 = *(const short8*)(qn + qrow + h * 64 + g * 8);
        short8 a1 = *(const short8*)(qn + qrow + h * 64 + 32 + g * 8);
        f32x4 sim[5];
#pragma unroll
        for (int tt = 0; tt < 5; ++tt) {
            const size_t kbase = ((size_t)(b * TPAD + tt * 16 + ln)) * 512 + h * 64;
            short8 b0 = *(const short8*)(kn + kbase + g * 8);
            short8 b1 = *(const short8*)(kn + kbase + 32 + g * 8);
            f32x4 c = (f32x4){0.f, 0.f, 0.f, 0.f};
            c = __builtin_amdgcn_mfma_f32_16x16x32_bf16(a0, b0, c, 0, 0, 0);
            c = __builtin_amdgcn_mfma_f32_16x16x32_bf16(a1, b1, c, 0, 0, 0);
            sim[tt] = c;
        }
#pragma unroll
        for (int i = 0; i < 4; ++i) {
            const float qs = lscale * s_inv[g * 4 + i];   // row = g*4+i (C/D layout)
            float v[5];
#pragma unroll
            for (int tt = 0; tt < 5; ++tt)
                v[tt] = (pm[tt] == 0.f) ? sim[tt][i] * qs : NEGINF;

            float lm = v[0];
#pragma unroll
            for (int tt = 1; tt < 5; ++tt) lm = fmaxf(lm, v[tt]);
            const float m1 = red16Max(lm);
            float lm2 = -3.0e38f;
#pragma unroll
            for (int tt = 0; tt < 5; ++tt) if (v[tt] < m1) lm2 = fmaxf(lm2, v[tt]);
            const float m2 = red16Max(lm2);
            float lm3 = -3.0e38f;
#pragma unroll
            for (int tt = 0; tt < 5; ++tt) if (v[tt] < m2) lm3 = fmaxf(lm3, v[tt]);
            const float m3 = red16Max(lm3);
            float lc = 0.f;
#pragma unroll
            for (int tt = 0; tt < 5; ++tt) {
                if (v[tt] >= m1) lc += 1.f;
                if (v[tt] >= m2) lc += 128.f;
            }
            const float cpk = red16Add(lc);
            const float c2 = floorf(cpk * (1.f / 128.f));
            const float c1 = cpk - 128.f * c2;
            const float th = (c1 >= 3.f) ? m1 : ((c2 >= 3.f) ? m2 : m3);

            float p[5], lsum = 0.f, lcnt = 0.f;
#pragma unroll
            for (int tt = 0; tt < 5; ++tt) {
                float pv = (v[tt] >= th) ? __expf(v[tt] - m1) : 0.f;
                p[tt] = pv;
                lsum += pv;
                lcnt += (pv > 0.f) ? 1.f : 0.f;
            }
            const float psum = red16Add(lsum);
            const float pcnt = red16Add(lcnt);
            const float inv = 1.f / fmaxf(psum, 1e-20f);

            float lmaxp = 0.f, lent = 0.f;
#pragma unroll
            for (int tt = 0; tt < 5; ++tt) {
                float a = p[tt] * inv;
                p[tt] = a;
                lmaxp = fmaxf(lmaxp, a);
                if (a > 0.f) {
                    float pp = fmaxf(a, 1e-8f);
                    lent += -pp * __logf(pp);
                }
            }
            const float maxp = red16Max(lmaxp);
            float ent = red16Add(lent);
            ent += (77.f - pcnt) * 1.8420680744e-7f;
            const float teff = fmaxf(pcnt, 2.f);
            const float entropy = fmaxf(ent / __logf(teff), 0.f);
            const float confh = fminf(fmaxf(maxp * (1.f - entropy), 0.f), 1.f);
            conf_acc[i] += confh;

#pragma unroll
            for (int tt = 0; tt < 5; ++tt)
                s_p[w][g * 4 + i][ln + tt * 16] = f2b(p[tt]);
        }
        short8 af[3];
#pragma unroll
        for (int k = 0; k < 3; ++k)
            af[k] = *(const short8*)(&s_p[w][ln][k * 32 + g * 8]);
        const size_t vtb = ((size_t)(b * NHEAD + h)) * 64;
#pragma unroll
        for (int n = 0; n < 4; ++n) {
            f32x4 o = (f32x4){0.f, 0.f, 0.f, 0.f};
#pragma unroll
            for (int k = 0; k < 3; ++k) {
                short8 bf = *(const short8*)(vt + (vtb + n * 16 + ln) * 96 + k * 32 + g * 8);
                o = __builtin_amdgcn_mfma_f32_16x16x32_bf16(af[k], bf, o, 0, 0, 0);
            }
#pragma unroll
            for (int i = 0; i < 4; ++i)
                aligned[((size_t)(b * NTOK + n0 + g * 4 + i)) * 512 + h * 64 + n * 16 + ln] =
                    f2b(o[i]);
        }
    }

    if (ln == 0) {
#pragma unroll
        for (int i = 0; i < 4; ++i) s_conf[w][g * 4 + i] = conf_acc[i];
    }
    __syncthreads();
    if (tid < 16) {
        float c = (s_conf[0][tid] + s_conf[1][tid] + s_conf[2][tid] + s_conf[3][tid]) * 0.125f;
        bypass[b * NTOK + n0 + tid] = (c >= 0.35f) ? 1.f : 0.f;
    }
}

// ---------------- host side ----------------
extern "C" void kernel_launch(void* const* d_in, const int* in_sizes, int n_in,
                              void* d_out, int out_size, void* d_ws, size_t ws_size,
                              hipStream_t stream)
{
    (void)in_sizes; (void)n_in; (void)out_size;
    if (ws_size < WS_NEED) return;

    const float* visual = (const float*)d_in[0];
    const float* text   = (const float*)d_in[1];
    const float* ln1_g  = (const float*)d_in[2];
    const float* ln1_b  = (const float*)d_in[3];
    const float* ln2_g  = (const float*)d_in[4];
    const float* ln2_b  = (const float*)d_in[5];
    const float* Wq = (const float*)d_in[6];   const float* bq = (const float*)d_in[7];
    const float* Wk = (const float*)d_in[8];   const float* bk = (const float*)d_in[9];
    const float* Wv = (const float*)d_in[10];  const float* bv = (const float*)d_in[11];
    const float* Wo = (const float*)d_in[12];  const float* bo = (const float*)d_in[13];
    const float* Wg = (const float*)d_in[14];  const float* bg = (const float*)d_in[15];
    const float* W1 = (const float*)d_in[16];  const float* b1 = (const float*)d_in[17];
    const float* W2 = (const float*)d_in[18];  const float* b2 = (const float*)d_in[19];
    const float* lsc = (const float*)d_in[20];
    const float* alp = (const float*)d_in[21];

    char* ws = (char*)d_ws;
    unsigned short* WQT  = (unsigned short*)(ws + OFF_WQT);
    unsigned short* WKT  = (unsigned short*)(ws + OFF_WKT);
    unsigned short* WVT  = (unsigned short*)(ws + OFF_WVT);
    unsigned short* WOT  = (unsigned short*)(ws + OFF_WOT);
    unsigned short* W1T  = (unsigned short*)(ws + OFF_W1T);
    unsigned short* W2T  = (unsigned short*)(ws + OFF_W2T);
    unsigned short* TEXTB = (unsigned short*)(ws + OFF_TEXTB);
    unsigned short* KFB  = (unsigned short*)(ws + OFF_KFB);
    unsigned short* KNRM = (unsigned short*)(ws + OFF_KNRM);
    float* PADM = (float*)(ws + OFF_PADM);
    float* GATE = (float*)(ws + OFF_GATE);
    float* BYP  = (float*)(ws + OFF_BYP);
    unsigned short* XB   = (unsigned short*)(ws + OFF_XB);
    unsigned short* BUFB = (unsigned short*)(ws + OFF_BUFB);
    unsigned short* BUFC = (unsigned short*)(ws + OFF_BUFC);
    unsigned short* HBUF = (unsigned short*)(ws + OFF_H);
    unsigned short* VT   = (unsigned short*)(ws + OFF_VT);   // overlays HBUF
    float* out = (float*)d_out;

    // 1) prep: all weight transposes + text bf16/padmask + VT pad zero-fill
    prep_kernel<<<3728, 256, 0, stream>>>(Wq, Wk, Wv, Wo, W1, W2,
                                          WQT, WKT, WVT, WOT, W1T, W2T,
                                          text, TEXTB, PADM, VT);

    // 2) LN1 + gate
    ln1_gate_kernel<<<MROWS, 128, 0, stream>>>(visual, ln1_g, ln1_b, Wg, bg, XB, GATE);

    // 3) text K/V projections in one launch (V writes VT directly) + K l2norm
    gemm_kv<<<dim3(5, 4, 2), 256, 0, stream>>>(TEXTB, WKT, WVT, bk, bv, KFB, VT);
    l2norm_kernel<<<640, 128, 0, stream>>>(KFB, KNRM);

    // 4) Q projection (raw q -> BUFB; l2norm fused into attn) — R10 gemm256
    gemm256<0><<<dim3(128 * 2), 512, 0, stream>>>(XB, WQT, bq, BUFB, nullptr, MROWS, 512, 512,
                                                  nullptr, nullptr, nullptr, nullptr, nullptr,
                                                  128, 2);

    // 5) fused attention (q-norm + allpad inside) -> aligned (BUFC), bypass
    attn_kernel<<<dim3(NTOK / 16, BATCH), 256, 0, stream>>>(BUFB, KNRM, VT, PADM, lsc,
                                                            BUFC, BYP);

    // 6) Wo projection + gated residual -> ypre (BUFB) — R10 gemm256
    gemm256<1><<<dim3(128 * 2), 512, 0, stream>>>(BUFC, WOT, bo, BUFB, nullptr, MROWS, 512, 512,
                                                  XB, GATE, BYP, nullptr, alp, 128, 2);

    // 7) LN2 -> yb (XB)
    ln2_kernel<<<MROWS, 128, 0, stream>>>(BUFB, ln2_g, ln2_b, XB);

    // 8) MLP — TRI-BUFFER counted-vmcnt experiment (HBUF reuses VT region)
    gemm256t<2><<<dim3(128 * 8), 512, 0, stream>>>(XB, W1T, b1, HBUF, nullptr, MROWS, HID, 512,
                                                   nullptr, nullptr, nullptr, nullptr, nullptr,
                                                   128, 8);
    gemm256t<3><<<dim3(128 * 2), 512, 0, stream>>>(HBUF, W2T, b2, nullptr, out, MROWS, 512, HID,
                                                   nullptr, nullptr, nullptr, XB, nullptr,
                                                   128, 2);
}

// Round 15
// 363.696 us; speedup vs baseline: 5.9478x; 1.0235x over previous
//
#include <hip/hip_runtime.h>
#include <stdint.h>

// ---------------- problem constants ----------------
#define BATCH 8
#define NTOK 4096          // 64*64
#define CDIM 512
#define TTXT 77
#define TPAD 80
#define NHEAD 8
#define HDIM 64
#define HID 2048           // 4*C
#define MROWS 32768        // B*NTOK
#define NEGINF (-1e30f)

typedef __attribute__((ext_vector_type(8))) short short8;
typedef __attribute__((ext_vector_type(4))) float f32x4;

__device__ __forceinline__ float b2f(unsigned short u) {
    union { unsigned int i; float f; } x; x.i = ((unsigned int)u) << 16; return x.f;
}
__device__ __forceinline__ unsigned short f2b(float f) {
    union { float f; unsigned int i; } x; x.f = f;
    unsigned int i = x.i;
    return (unsigned short)((i + 0x7fffu + ((i >> 16) & 1u)) >> 16);
}

// async global->LDS, 16B per lane; LDS dest must be linear in lane order
__device__ __forceinline__ void gload16(const void* g, void* l) {
    __builtin_amdgcn_global_load_lds(
        (const __attribute__((address_space(1))) unsigned int*)g,
        (__attribute__((address_space(3))) unsigned int*)l, 16, 0, 0);
}

// ---------------- workspace layout (bytes) ----------------
#define OFF_WQT   ((size_t)0)
#define OFF_WKT   (OFF_WQT + 512*512*2)
#define OFF_WVT   (OFF_WKT + 512*512*2)
#define OFF_WOT   (OFF_WVT + 512*512*2)
#define OFF_W1T   (OFF_WOT + 512*512*2)
#define OFF_W2T   (OFF_W1T + (size_t)2048*512*2)
#define OFF_TEXTB (OFF_W2T + (size_t)512*2048*2)
#define OFF_KFB   (OFF_TEXTB + (size_t)640*512*2)
#define OFF_KNRM  (OFF_KFB + (size_t)640*512*2)
#define OFF_VPAD  (OFF_KNRM + (size_t)640*512*2)
#define OFF_PADM  (OFF_VPAD + (size_t)640*512*2)
#define OFF_ALLP  (OFF_PADM + 2560)
#define OFF_GATE  (OFF_ALLP + 256)
#define OFF_BYP   (OFF_GATE + (size_t)MROWS*4)
#define OFF_XB    (OFF_BYP + (size_t)MROWS*4)
#define OFF_BUFB  (OFF_XB + (size_t)MROWS*CDIM*2)
#define OFF_BUFC  (OFF_BUFB + (size_t)MROWS*CDIM*2)
#define OFF_H     (OFF_BUFC + (size_t)MROWS*CDIM*2)
#define WS_NEED   (OFF_H + (size_t)MROWS*HID*2)
// VT overlays HBUF (dead until the MLP phase): [B*NHEAD][64][96] bf16 = 768 KiB
#define OFF_VT    OFF_H

// ---------------- small helpers ----------------
__device__ __forceinline__ float waveReduceAdd(float v) {
#pragma unroll
    for (int m = 1; m < 64; m <<= 1) v += __shfl_xor(v, m);
    return v;
}
__device__ __forceinline__ float red16Max(float v) {
#pragma unroll
    for (int m = 1; m < 16; m <<= 1) v = fmaxf(v, __shfl_xor(v, m));
    return v;
}
__device__ __forceinline__ float red16Add(float v) {
#pragma unroll
    for (int m = 1; m < 16; m <<= 1) v += __shfl_xor(v, m);
    return v;
}
__device__ __forceinline__ float red16Min(float v) {
#pragma unroll
    for (int m = 1; m < 16; m <<= 1) v = fminf(v, __shfl_xor(v, m));
    return v;
}

// ---------------- prep mega-kernel ----------------
// blocks [0,3072): 6 weight transposes fp32 [R][C] -> bf16 [C][R]
// blocks [3072,3712): text rows -> bf16 (padded to 80/batch) + pad mask
// blocks [3712,3728): zero-fill VT pad slots t in [80,96)
__global__ __launch_bounds__(256) void prep_kernel(
    const float* __restrict__ Wq, const float* __restrict__ Wk,
    const float* __restrict__ Wv, const float* __restrict__ Wo,
    const float* __restrict__ W1, const float* __restrict__ W2,
    unsigned short* __restrict__ WQT, unsigned short* __restrict__ WKT,
    unsigned short* __restrict__ WVT, unsigned short* __restrict__ WOT,
    unsigned short* __restrict__ W1T, unsigned short* __restrict__ W2T,
    const float* __restrict__ text, unsigned short* __restrict__ textb,
    float* __restrict__ padm, unsigned short* __restrict__ vt)
{
    __shared__ float tile[32][33];
    __shared__ float sred[4];
    int b = blockIdx.x;
    const int tid = threadIdx.x;

    if (b >= 3712) {
        const int i = b - 3712;
        const int bh = i * 4 + (tid >> 6), d = tid & 63;
        uint4 z = {0u, 0u, 0u, 0u};
        uint4* p = (uint4*)(vt + ((size_t)bh * 64 + d) * 96 + 80);
        p[0] = z; p[1] = z;
        return;
    }
    if (b >= 3072) {
        const int r = b - 3072;                 // 0..639
        const int tb = r / TPAD, t = r % TPAD;
        if (t < TTXT) {
            const float2 v = ((const float2*)(text + ((size_t)(tb * TTXT + t)) * 512))[tid];
            float a = fabsf(v.x) + fabsf(v.y);
            a = waveReduceAdd(a);
            if ((tid & 63) == 0) sred[tid >> 6] = a;
            __syncthreads();
            const float asum = sred[0] + sred[1] + sred[2] + sred[3];
            ushort2 o; o.x = f2b(v.x); o.y = f2b(v.y);
            ((ushort2*)(textb + (size_t)r * 512))[tid] = o;
            if (tid == 0) padm[r] = (asum <= 1e-6f) ? 1.f : 0.f;
        } else {
            ushort2 z; z.x = 0; z.y = 0;
            ((ushort2*)(textb + (size_t)r * 512))[tid] = z;
            if (tid == 0) padm[r] = 1.f;
        }
        return;
    }

    const float* src; unsigned short* dst; int R, C, cx, ry;
    if (b < 1024)       { src = W1; dst = W1T; R = 512;  C = 2048; cx = b & 63; ry = b >> 6; }
    else if (b < 2048)  { b -= 1024; src = W2; dst = W2T; R = 2048; C = 512; cx = b & 15; ry = b >> 4; }
    else {
        b -= 2048; const int which = b >> 8; b &= 255;
        R = 512; C = 512; cx = b & 15; ry = b >> 4;
        src = (which == 0) ? Wq : (which == 1) ? Wk : (which == 2) ? Wv : Wo;
        dst = (which == 0) ? WQT : (which == 1) ? WKT : (which == 2) ? WVT : WOT;
    }
    const int tx = threadIdx.x & 31, ty = threadIdx.x >> 5;  // ty 0..7
    const int c0 = cx * 32, r0 = ry * 32;
#pragma unroll
    for (int i = 0; i < 32; i += 8)
        tile[ty + i][tx] = src[(size_t)(r0 + ty + i) * C + c0 + tx];
    __syncthreads();
#pragma unroll
    for (int i = 0; i < 32; i += 8)
        dst[(size_t)(c0 + ty + i) * R + r0 + tx] = f2b(tile[tx][ty + i]);
}

// ---------------- LN1 + gate ----------------
__global__ __launch_bounds__(128) void ln1_gate_kernel(
    const float* __restrict__ vin, const float* __restrict__ g1, const float* __restrict__ b1v,
    const float* __restrict__ Wg, const float* __restrict__ bg,
    unsigned short* __restrict__ xb, float* __restrict__ gate)
{
    __shared__ float sred[4];
    const int row = blockIdx.x, tid = threadIdx.x;
    const float4 v = *(const float4*)(vin + (size_t)row * 512 + tid * 4);
    float s = v.x + v.y + v.z + v.w;
    float s2 = v.x * v.x + v.y * v.y + v.z * v.z + v.w * v.w;
    s = waveReduceAdd(s); s2 = waveReduceAdd(s2);
    if ((tid & 63) == 0) { sred[tid >> 6] = s; sred[2 + (tid >> 6)] = s2; }
    __syncthreads();
    s = sred[0] + sred[1]; s2 = sred[2] + sred[3];
    const float mu = s * (1.f / 512.f);
    float var = s2 * (1.f / 512.f) - mu * mu;
    const float rs = rsqrtf(fmaxf(var, 0.f) + 1e-5f);
    const float4 gg = *(const float4*)(g1 + tid * 4);
    const float4 bb = *(const float4*)(b1v + tid * 4);
    const float x0 = (v.x - mu) * rs * gg.x + bb.x;
    const float x1 = (v.y - mu) * rs * gg.y + bb.y;
    const float x2 = (v.z - mu) * rs * gg.z + bb.z;
    const float x3 = (v.w - mu) * rs * gg.w + bb.w;
    ushort4 o; o.x = f2b(x0); o.y = f2b(x1); o.z = f2b(x2); o.w = f2b(x3);
    *(ushort4*)(xb + (size_t)row * 512 + tid * 4) = o;
    const float4 wg = *(const float4*)(Wg + tid * 4);
    float gp = x0 * wg.x + x1 * wg.y + x2 * wg.z + x3 * wg.w;
    gp = waveReduceAdd(gp);
    __syncthreads();
    if ((tid & 63) == 0) sred[tid >> 6] = gp;
    __syncthreads();
    if (tid == 0) {
        float z = sred[0] + sred[1] + bg[0];
        gate[row] = 1.f / (1.f + __expf(-z));
    }
}

// ---------------- LN2 ----------------
__global__ __launch_bounds__(128) void ln2_kernel(
    const unsigned short* __restrict__ yin, const float* __restrict__ g2, const float* __restrict__ b2v,
    unsigned short* __restrict__ yb)
{
    __shared__ float sred[4];
    const int row = blockIdx.x, tid = threadIdx.x;
    ushort4 u = *(const ushort4*)(yin + (size_t)row * 512 + tid * 4);
    float v0 = b2f(u.x), v1 = b2f(u.y), v2 = b2f(u.z), v3 = b2f(u.w);
    float s = v0 + v1 + v2 + v3;
    float s2 = v0 * v0 + v1 * v1 + v2 * v2 + v3 * v3;
    s = waveReduceAdd(s); s2 = waveReduceAdd(s2);
    if ((tid & 63) == 0) { sred[tid >> 6] = s; sred[2 + (tid >> 6)] = s2; }
    __syncthreads();
    s = sred[0] + sred[1]; s2 = sred[2] + sred[3];
    const float mu = s * (1.f / 512.f);
    float var = s2 * (1.f / 512.f) - mu * mu;
    const float rs = rsqrtf(fmaxf(var, 0.f) + 1e-5f);
    const float4 gg = *(const float4*)(g2 + tid * 4);
    const float4 bb = *(const float4*)(b2v + tid * 4);
    ushort4 o;
    o.x = f2b((v0 - mu) * rs * gg.x + bb.x);
    o.y = f2b((v1 - mu) * rs * gg.y + bb.y);
    o.z = f2b((v2 - mu) * rs * gg.z + bb.z);
    o.w = f2b((v3 - mu) * rs * gg.w + bb.w);
    *(ushort4*)(yb + (size_t)row * 512 + tid * 4) = o;
}

// ---------------- row l2-normalize bf16 -> bf16 (K only, 640 rows) ----------------
__global__ __launch_bounds__(128) void l2norm_kernel(
    const unsigned short* __restrict__ in, unsigned short* __restrict__ out)
{
    __shared__ float sred[2];
    const int row = blockIdx.x, tid = threadIdx.x;
    ushort4 u = *(const ushort4*)(in + (size_t)row * 512 + tid * 4);
    float v0 = b2f(u.x), v1 = b2f(u.y), v2 = b2f(u.z), v3 = b2f(u.w);
    float ss = v0 * v0 + v1 * v1 + v2 * v2 + v3 * v3;
    ss = waveReduceAdd(ss);
    if ((tid & 63) == 0) sred[tid >> 6] = ss;
    __syncthreads();
    ss = sred[0] + sred[1];
    const float inv = 1.f / fmaxf(sqrtf(ss), 1e-6f);
    ushort4 o;
    o.x = f2b(v0 * inv); o.y = f2b(v1 * inv); o.z = f2b(v2 * inv); o.w = f2b(v3 * inv);
    *(ushort4*)(out + (size_t)row * 512 + tid * 4) = o;
}

// ---------------- merged text K/V GEMM (128x128, M=640) ----------------
// grid (5,4,2): z=0 -> KFB (row-major bf16); z=1 -> VT direct (per-head transposed)
__global__ __launch_bounds__(256) void gemm_kv(
    const unsigned short* __restrict__ A,
    const unsigned short* __restrict__ BtK, const unsigned short* __restrict__ BtV,
    const float* __restrict__ bk, const float* __restrict__ bv,
    unsigned short* __restrict__ kfb, unsigned short* __restrict__ vt)
{
    const int K = 512, N = 512;
    const unsigned short* Bt = blockIdx.z ? BtV : BtK;
    const float* bias = blockIdx.z ? bv : bk;
    __shared__ unsigned short sA[128 * 64];
    __shared__ unsigned short sB[128 * 64];
    char* cA = (char*)sA;
    char* cB = (char*)sB;
    const int tid = threadIdx.x;
    const int lane = tid & 63, w = tid >> 6;
    const int g = lane >> 4, ln = lane & 15;
    const int WR = w >> 1, WC = w & 1;
    const int rowA0 = blockIdx.x * 128, colB0 = blockIdx.y * 128;

    f32x4 acc[4][4];
#pragma unroll
    for (int m = 0; m < 4; ++m)
#pragma unroll
        for (int n = 0; n < 4; ++n) acc[m][n] = (f32x4){0.f, 0.f, 0.f, 0.f};

    for (int k0 = 0; k0 < K; k0 += 64) {
        __syncthreads();
#pragma unroll
        for (int i = 0; i < 4; ++i) {
            int c = tid + i * 256;
            int row = c >> 3, kc = c & 7;
            int kcs = kc ^ (row & 7);
            gload16(A + (size_t)(rowA0 + row) * K + k0 + kcs * 8, cA + c * 16);
            gload16(Bt + (size_t)(colB0 + row) * K + k0 + kcs * 8, cB + c * 16);
        }
        __syncthreads();
#pragma unroll
        for (int kk = 0; kk < 2; ++kk) {
            short8 af[4], bf[4];
#pragma unroll
            for (int m = 0; m < 4; ++m) {
                int row = WR * 64 + m * 16 + ln;
                af[m] = *(const short8*)(cA + row * 128 + ((kk * 64 + g * 16) ^ ((row & 7) << 4)));
            }
#pragma unroll
            for (int n = 0; n < 4; ++n) {
                int col = WC * 64 + n * 16 + ln;
                bf[n] = *(const short8*)(cB + col * 128 + ((kk * 64 + g * 16) ^ ((col & 7) << 4)));
            }
#pragma unroll
            for (int m = 0; m < 4; ++m)
#pragma unroll
                for (int n = 0; n < 4; ++n)
                    acc[m][n] = __builtin_amdgcn_mfma_f32_16x16x32_bf16(af[m], bf[n], acc[m][n], 0, 0, 0);
        }
    }

#pragma unroll
    for (int m = 0; m < 4; ++m) {
        const int rbase = rowA0 + WR * 64 + m * 16 + g * 4;
#pragma unroll
        for (int n = 0; n < 4; ++n) {
            const int col = colB0 + WC * 64 + n * 16 + ln;
            const float bcol = bias[col];
#pragma unroll
            for (int i = 0; i < 4; ++i) {
                const int row = rbase + i;
                const float v = acc[m][n][i] + bcol;
                if (blockIdx.z == 0) {
                    kfb[(size_t)row * N + col] = f2b(v);
                } else {
                    const int tb = row / TPAD, t = row - tb * TPAD;
                    const int h = col >> 6, d = col & 63;
                    vt[((size_t)(tb * NHEAD + h) * 64 + d) * 96 + t] = f2b(v);
                }
            }
        }
    }
}

// ---------------- 256x256 bf16 MFMA GEMM, R10 best-known (all big GEMMs) ----------------
// Low-barrier schedule: stage depth-1 into buf^1 (never the live buffer), ONE
// vmcnt(0)+barrier per K-tile; 4 quadrant phases with setprio MFMA clusters;
// sched_barrier(VALU|SALU|DS_READ) seams. Measured best: 362.5 us total (R10).
#define SEAM() __builtin_amdgcn_sched_barrier(0x106)

template<int EPI>
__global__ __launch_bounds__(512, 2) void gemm256(
    const unsigned short* __restrict__ A, const unsigned short* __restrict__ Bt,
    const float* __restrict__ bias,
    unsigned short* __restrict__ outb, float* __restrict__ outf,
    int M, int N, int K,
    const unsigned short* __restrict__ xres, const float* __restrict__ gate,
    const float* __restrict__ byp, const unsigned short* __restrict__ yres,
    const float* __restrict__ alphaPtr, int gxM, int gyN)
{
    __shared__ unsigned short lds[2][2][16384];   // [buf][A/B][256*64] = 128 KiB
    const int tid = threadIdx.x;
    const int lane = tid & 63, w = tid >> 6;
    const int g = lane >> 4, ln = lane & 15;
    const int wr = w >> 2, wc = w & 3;

    // XCD-chunked bijective swizzle
    int bm, bn;
    {
        const int L = (int)blockIdx.x;
        const int xcd = L & 7, j = L >> 3;
        const int rl = j / gyN;
        bn = j - rl * gyN;
        bm = xcd * (gxM >> 3) + rl;
    }
    const int rowA0 = bm * 256, colB0 = bn * 256;
    const int nt = K >> 6;

    auto stageA = [&](int t, int mh) {
        const int buf = t & 1;
#pragma unroll
        for (int r = 0; r < 2; ++r) {
            const int c = tid + r * 512;
            const int prl = c >> 3, kc = c & 7;
            const int grow = rowA0 + ((prl >> 6) << 7) + (mh << 6) + (prl & 63);
            gload16(A + (size_t)grow * K + (t << 6) + ((kc ^ (prl & 7)) << 3),
                    (char*)&lds[buf][0][mh * 8192] + c * 16);
        }
    };
    auto stageB = [&](int t, int nh) {
        const int buf = t & 1;
#pragma unroll
        for (int r = 0; r < 2; ++r) {
            const int c = tid + r * 512;
            const int prl = c >> 3, kc = c & 7;
            const int gcol = colB0 + ((prl >> 5) << 6) + (nh << 5) + (prl & 31);
            gload16(Bt + (size_t)gcol * K + (t << 6) + ((kc ^ (prl & 7)) << 3),
                    (char*)&lds[buf][1][nh * 8192] + c * 16);
        }
    };

    f32x4 acc[8][4];
#pragma unroll
    for (int m = 0; m < 8; ++m)
#pragma unroll
        for (int n = 0; n < 4; ++n) acc[m][n] = (f32x4){0.f, 0.f, 0.f, 0.f};

    // prologue: stage tile 0 fully; drain; barrier  (fill = 1 tile)
    stageA(0, 0); stageA(0, 1); stageB(0, 0); stageB(0, 1);
    asm volatile("s_waitcnt vmcnt(0)" ::: "memory");
    __builtin_amdgcn_s_barrier();

    const int sw  = (ln & 7) << 4;
    const int kb0 = (g * 16) ^ sw;
    const int kb1 = (64 + g * 16) ^ sw;
    const int arow = (wr * 64 + ln) * 128;
    const int brow = (wc * 32 + ln) * 128;

    short8 afr[4][2], bfr[4][2];

#pragma unroll 2
    for (int t = 0; t < nt; ++t) {
        const char* lA = (const char*)&lds[t & 1][0][0];
        const char* lB = (const char*)&lds[t & 1][1][0];
        const bool pf = (t + 1 < nt);

        // ---- q0: (m0-3, n0-1), 12 ds_reads; stage A(t+1) both halves ----
#pragma unroll
        for (int m = 0; m < 4; ++m) {
            afr[m][0] = *(const short8*)(lA + arow + m * 2048 + kb0);
            afr[m][1] = *(const short8*)(lA + arow + m * 2048 + kb1);
        }
#pragma unroll
        for (int n = 0; n < 2; ++n) {
            bfr[n][0] = *(const short8*)(lB + brow + n * 2048 + kb0);
            bfr[n][1] = *(const short8*)(lB + brow + n * 2048 + kb1);
        }
        if (pf) { stageA(t + 1, 0); stageA(t + 1, 1); }
        __builtin_amdgcn_s_setprio(1);
#pragma unroll
        for (int m = 0; m < 4; ++m)
#pragma unroll
            for (int n = 0; n < 2; ++n) {
                acc[m][n] = __builtin_amdgcn_mfma_f32_16x16x32_bf16(afr[m][0], bfr[n][0], acc[m][n], 0, 0, 0);
                acc[m][n] = __builtin_amdgcn_mfma_f32_16x16x32_bf16(afr[m][1], bfr[n][1], acc[m][n], 0, 0, 0);
            }
        __builtin_amdgcn_s_setprio(0);
        SEAM();

        // ---- q1: (m0-3, n2-3), 4 ds_reads; stage B(t+1) both halves ----
#pragma unroll
        for (int n = 2; n < 4; ++n) {
            bfr[n][0] = *(const short8*)(lB + brow + (n & 1) * 2048 + 16384 + kb0);
            bfr[n][1] = *(const short8*)(lB + brow + (n & 1) * 2048 + 16384 + kb1);
        }
        if (pf) { stageB(t + 1, 0); stageB(t + 1, 1); }
        __builtin_amdgcn_s_setprio(1);
#pragma unroll
        for (int m = 0; m < 4; ++m)
#pragma unroll
            for (int n = 2; n < 4; ++n) {
                acc[m][n] = __builtin_amdgcn_mfma_f32_16x16x32_bf16(afr[m][0], bfr[n][0], acc[m][n], 0, 0, 0);
                acc[m][n] = __builtin_amdgcn_mfma_f32_16x16x32_bf16(afr[m][1], bfr[n][1], acc[m][n], 0, 0, 0);
            }
        __builtin_amdgcn_s_setprio(0);
        SEAM();

        // ---- q2: (m4-7, n0-1), 8 ds_reads ----
#pragma unroll
        for (int m = 0; m < 4; ++m) {
            afr[m][0] = *(const short8*)(lA + arow + m * 2048 + 16384 + kb0);
            afr[m][1] = *(const short8*)(lA + arow + m * 2048 + 16384 + kb1);
        }
        __builtin_amdgcn_s_setprio(1);
#pragma unroll
        for (int m = 0; m < 4; ++m)
#pragma unroll
            for (int n = 0; n < 2; ++n) {
                acc[m + 4][n] = __builtin_amdgcn_mfma_f32_16x16x32_bf16(afr[m][0], bfr[n][0], acc[m + 4][n], 0, 0, 0);
                acc[m + 4][n] = __builtin_amdgcn_mfma_f32_16x16x32_bf16(afr[m][1], bfr[n][1], acc[m + 4][n], 0, 0, 0);
            }
        __builtin_amdgcn_s_setprio(0);
        SEAM();

        // ---- q3: (m4-7, n2-3), 0 ds_reads ----
        __builtin_amdgcn_s_setprio(1);
#pragma unroll
        for (int m = 0; m < 4; ++m)
#pragma unroll
            for (int n = 2; n < 4; ++n) {
                acc[m + 4][n] = __builtin_amdgcn_mfma_f32_16x16x32_bf16(afr[m][0], bfr[n][0], acc[m + 4][n], 0, 0, 0);
                acc[m + 4][n] = __builtin_amdgcn_mfma_f32_16x16x32_bf16(afr[m][1], bfr[n][1], acc[m + 4][n], 0, 0, 0);
            }
        __builtin_amdgcn_s_setprio(0);

        // ---- tile boundary: t+1 fully landed; all waves past tile-t reads ----
        if (pf) {
            asm volatile("s_waitcnt vmcnt(0)" ::: "memory");
            __builtin_amdgcn_s_barrier();
        }
    }

    // ---- epilogue ----
    const float alpha = (EPI == 1) ? *alphaPtr : 0.f;
#pragma unroll
    for (int m = 0; m < 8; ++m) {
        const int rbase = rowA0 + wr * 128 + m * 16 + g * 4;
#pragma unroll
        for (int n = 0; n < 4; ++n) {
            const int col = colB0 + wc * 64 + n * 16 + ln;
            const float bcol = bias[col];
#pragma unroll
            for (int i = 0; i < 4; ++i) {
                const int row = rbase + i;
                const float v = acc[m][n][i] + bcol;
                if (EPI == 0) {
                    outb[(size_t)row * N + col] = f2b(v);
                } else if (EPI == 1) {
                    float yp = b2f(xres[(size_t)row * N + col]) + alpha * gate[row] * byp[row] * v;
                    outb[(size_t)row * N + col] = f2b(yp);
                } else if (EPI == 2) {
                    const float u2 = 2.f * v * (0.7978845608f + 0.0356774081f * v * v);
                    const float tt = 1.f - 2.f / (__expf(u2) + 1.f);
                    outb[(size_t)row * N + col] = f2b(0.5f * v * (1.f + tt));
                } else {
                    outf[(size_t)row * N + col] = b2f(yres[(size_t)row * N + col]) + v;
                }
            }
        }
    }
}
#undef SEAM

// ---------------- fused attention (q-l2norm + allpad fused in) ----------------
// grid: (NTOK/16, B), block 256 = 4 waves; each wave: same 16 rows, heads {w, w+4}.
__global__ __launch_bounds__(256) void attn_kernel(
    const unsigned short* __restrict__ qn,   // [MROWS,512] raw q, bf16
    const unsigned short* __restrict__ kn,   // [B,80,512] l2-normed k, bf16
    const unsigned short* __restrict__ vt,   // [B*8][64][96] per-head V^T, bf16
    const float* __restrict__ padm,          // [B,80] 1.0 = pad
    const float* __restrict__ lscPtr,
    unsigned short* __restrict__ aligned,    // [MROWS,512] bf16
    float* __restrict__ bypass)              // [MROWS]
{
    const int b = blockIdx.y;
    const int n0 = blockIdx.x * 16;
    const int tid = threadIdx.x;
    const int w = tid >> 6, lane = tid & 63, g = lane >> 4, ln = lane & 15;
    __shared__ unsigned short s_p[4][16][104];
    __shared__ float s_conf[4][16];
    __shared__ float s_inv[16];

    // pad-mask of this lane's 5 t-columns (depends only on ln)
    float pm[5];
#pragma unroll
    for (int tt = 0; tt < 5; ++tt) {
        int t = ln + tt * 16;
        pm[tt] = (t < TTXT) ? padm[b * TPAD + t] : 1.f;
    }
    // all-pad check (fused allpad): min over t<77 of padm
    {
        float pmn = fminf(fminf(pm[0], pm[1]), fminf(fminf(pm[2], pm[3]), pm[4]));
        pmn = red16Min(pmn);
        if (pmn > 0.5f) {
            uint4 z = {0u, 0u, 0u, 0u};
#pragma unroll
            for (int j = 0; j < 4; ++j) {
                int id = tid + j * 256;
                int row = id >> 6, c8 = id & 63;
                *(uint4*)(aligned + ((size_t)(b * NTOK + n0 + row)) * 512 + c8 * 8) = z;
            }
            if (tid < 16) bypass[b * NTOK + n0 + tid] = 0.f;
            return;
        }
    }

    // ---- q-norm preamble: 16 rows x 512 ch; thread (r=tid>>4, seg=tid&15) ----
    {
        const int r = tid >> 4, seg = tid & 15;
        const unsigned short* qp = qn + ((size_t)(b * NTOK + n0 + r)) * 512 + seg * 32;
        float ss = 0.f;
#pragma unroll
        for (int j = 0; j < 4; ++j) {
            short8 u = *(const short8*)(qp + j * 8);
#pragma unroll
            for (int e = 0; e < 8; ++e) {
                float f = b2f(((const unsigned short*)&u)[e]);
                ss += f * f;
            }
        }
        ss = red16Add(ss);
        if (seg == 0) s_inv[r] = 1.f / fmaxf(sqrtf(ss), 1e-6f);
    }

    float lscale;
    {
        float ls = *lscPtr;
        ls = fminf(fmaxf(ls, -2.f), 2.f);
        lscale = __expf(ls) * 0.125f;
    }

    for (int j = g; j < 24; j += 4) s_p[w][ln][80 + j] = 0;
    __syncthreads();                               // s_inv ready

    float conf_acc[4] = {0.f, 0.f, 0.f, 0.f};
    const size_t qrow = ((size_t)(b * NTOK + n0 + ln)) * 512;

#pragma unroll
    for (int hh = 0; hh < 2; ++hh) {
        const int h = w + hh * 4;
        short8 a0 = *(const short8*)(qn + qrow + h * 64 + g * 8);
        short8 a1 = *(const short8*)(qn + qrow + h * 64 + 32 + g * 8);
        f32x4 sim[5];
#pragma unroll
        for (int tt = 0; tt < 5; ++tt) {
            const size_t kbase = ((size_t)(b * TPAD + tt * 16 + ln)) * 512 + h * 64;
            short8 b0 = *(const short8*)(kn + kbase + g * 8);
            short8 b1 = *(const short8*)(kn + kbase + 32 + g * 8);
            f32x4 c = (f32x4){0.f, 0.f, 0.f, 0.f};
            c = __builtin_amdgcn_mfma_f32_16x16x32_bf16(a0, b0, c, 0, 0, 0);
            c = __builtin_amdgcn_mfma_f32_16x16x32_bf16(a1, b1, c, 0, 0, 0);
            sim[tt] = c;
        }
#pragma unroll
        for (int i = 0; i < 4; ++i) {
            const float qs = lscale * s_inv[g * 4 + i];   // row = g*4+i (C/D layout)
            float v[5];
#pragma unroll
            for (int tt = 0; tt < 5; ++tt)
                v[tt] = (pm[tt] == 0.f) ? sim[tt][i] * qs : NEGINF;

            float lm = v[0];
#pragma unroll
            for (int tt = 1; tt < 5; ++tt) lm = fmaxf(lm, v[tt]);
            const float m1 = red16Max(lm);
            float lm2 = -3.0e38f;
#pragma unroll
            for (int tt = 0; tt < 5; ++tt) if (v[tt] < m1) lm2 = fmaxf(lm2, v[tt]);
            const float m2 = red16Max(lm2);
            float lm3 = -3.0e38f;
#pragma unroll
            for (int tt = 0; tt < 5; ++tt) if (v[tt] < m2) lm3 = fmaxf(lm3, v[tt]);
            const float m3 = red16Max(lm3);
            // packed count reduction: c1 + 128*c2 (both <= 80 < 128)
            float lc = 0.f;
#pragma unroll
            for (int tt = 0; tt < 5; ++tt) {
                if (v[tt] >= m1) lc += 1.f;
                if (v[tt] >= m2) lc += 128.f;
            }
            const float cpk = red16Add(lc);
            const float c2 = floorf(cpk * (1.f / 128.f));
            const float c1 = cpk - 128.f * c2;
            const float th = (c1 >= 3.f) ? m1 : ((c2 >= 3.f) ? m2 : m3);

            float p[5], lsum = 0.f, lcnt = 0.f;
#pragma unroll
            for (int tt = 0; tt < 5; ++tt) {
                float pv = (v[tt] >= th) ? __expf(v[tt] - m1) : 0.f;
                p[tt] = pv;
                lsum += pv;
                lcnt += (pv > 0.f) ? 1.f : 0.f;
            }
            const float psum = red16Add(lsum);
            const float pcnt = red16Add(lcnt);
            const float inv = 1.f / fmaxf(psum, 1e-20f);

            float lmaxp = 0.f, lent = 0.f;
#pragma unroll
            for (int tt = 0; tt < 5; ++tt) {
                float a = p[tt] * inv;
                p[tt] = a;
                lmaxp = fmaxf(lmaxp, a);
                if (a > 0.f) {
                    float pp = fmaxf(a, 1e-8f);
                    lent += -pp * __logf(pp);
                }
            }
            const float maxp = red16Max(lmaxp);
            float ent = red16Add(lent);
            ent += (77.f - pcnt) * 1.8420680744e-7f;
            const float teff = fmaxf(pcnt, 2.f);
            const float entropy = fmaxf(ent / __logf(teff), 0.f);
            const float confh = fminf(fmaxf(maxp * (1.f - entropy), 0.f), 1.f);
            conf_acc[i] += confh;

#pragma unroll
            for (int tt = 0; tt < 5; ++tt)
                s_p[w][g * 4 + i][ln + tt * 16] = f2b(p[tt]);
        }
        short8 af[3];
#pragma unroll
        for (int k = 0; k < 3; ++k)
            af[k] = *(const short8*)(&s_p[w][ln][k * 32 + g * 8]);
        const size_t vtb = ((size_t)(b * NHEAD + h)) * 64;
#pragma unroll
        for (int n = 0; n < 4; ++n) {
            f32x4 o = (f32x4){0.f, 0.f, 0.f, 0.f};
#pragma unroll
            for (int k = 0; k < 3; ++k) {
                short8 bf = *(const short8*)(vt + (vtb + n * 16 + ln) * 96 + k * 32 + g * 8);
                o = __builtin_amdgcn_mfma_f32_16x16x32_bf16(af[k], bf, o, 0, 0, 0);
            }
#pragma unroll
            for (int i = 0; i < 4; ++i)
                aligned[((size_t)(b * NTOK + n0 + g * 4 + i)) * 512 + h * 64 + n * 16 + ln] =
                    f2b(o[i]);
        }
    }

    if (ln == 0) {
#pragma unroll
        for (int i = 0; i < 4; ++i) s_conf[w][g * 4 + i] = conf_acc[i];
    }
    __syncthreads();
    if (tid < 16) {
        float c = (s_conf[0][tid] + s_conf[1][tid] + s_conf[2][tid] + s_conf[3][tid]) * 0.125f;
        bypass[b * NTOK + n0 + tid] = (c >= 0.35f) ? 1.f : 0.f;
    }
}

// ---------------- host side ----------------
extern "C" void kernel_launch(void* const* d_in, const int* in_sizes, int n_in,
                              void* d_out, int out_size, void* d_ws, size_t ws_size,
                              hipStream_t stream)
{
    (void)in_sizes; (void)n_in; (void)out_size;
    if (ws_size < WS_NEED) return;

    const float* visual = (const float*)d_in[0];
    const float* text   = (const float*)d_in[1];
    const float* ln1_g  = (const float*)d_in[2];
    const float* ln1_b  = (const float*)d_in[3];
    const float* ln2_g  = (const float*)d_in[4];
    const float* ln2_b  = (const float*)d_in[5];
    const float* Wq = (const float*)d_in[6];   const float* bq = (const float*)d_in[7];
    const float* Wk = (const float*)d_in[8];   const float* bk = (const float*)d_in[9];
    const float* Wv = (const float*)d_in[10];  const float* bv = (const float*)d_in[11];
    const float* Wo = (const float*)d_in[12];  const float* bo = (const float*)d_in[13];
    const float* Wg = (const float*)d_in[14];  const float* bg = (const float*)d_in[15];
    const float* W1 = (const float*)d_in[16];  const float* b1 = (const float*)d_in[17];
    const float* W2 = (const float*)d_in[18];  const float* b2 = (const float*)d_in[19];
    const float* lsc = (const float*)d_in[20];
    const float* alp = (const float*)d_in[21];

    char* ws = (char*)d_ws;
    unsigned short* WQT  = (unsigned short*)(ws + OFF_WQT);
    unsigned short* WKT  = (unsigned short*)(ws + OFF_WKT);
    unsigned short* WVT  = (unsigned short*)(ws + OFF_WVT);
    unsigned short* WOT  = (unsigned short*)(ws + OFF_WOT);
    unsigned short* W1T  = (unsigned short*)(ws + OFF_W1T);
    unsigned short* W2T  = (unsigned short*)(ws + OFF_W2T);
    unsigned short* TEXTB = (unsigned short*)(ws + OFF_TEXTB);
    unsigned short* KFB  = (unsigned short*)(ws + OFF_KFB);
    unsigned short* KNRM = (unsigned short*)(ws + OFF_KNRM);
    float* PADM = (float*)(ws + OFF_PADM);
    float* GATE = (float*)(ws + OFF_GATE);
    float* BYP  = (float*)(ws + OFF_BYP);
    unsigned short* XB   = (unsigned short*)(ws + OFF_XB);
    unsigned short* BUFB = (unsigned short*)(ws + OFF_BUFB);
    unsigned short* BUFC = (unsigned short*)(ws + OFF_BUFC);
    unsigned short* HBUF = (unsigned short*)(ws + OFF_H);
    unsigned short* VT   = (unsigned short*)(ws + OFF_VT);   // overlays HBUF
    float* out = (float*)d_out;

    // 1) prep: all weight transposes + text bf16/padmask + VT pad zero-fill
    prep_kernel<<<3728, 256, 0, stream>>>(Wq, Wk, Wv, Wo, W1, W2,
                                          WQT, WKT, WVT, WOT, W1T, W2T,
                                          text, TEXTB, PADM, VT);

    // 2) LN1 + gate
    ln1_gate_kernel<<<MROWS, 128, 0, stream>>>(visual, ln1_g, ln1_b, Wg, bg, XB, GATE);

    // 3) text K/V projections in one launch (V writes VT directly) + K l2norm
    gemm_kv<<<dim3(5, 4, 2), 256, 0, stream>>>(TEXTB, WKT, WVT, bk, bv, KFB, VT);
    l2norm_kernel<<<640, 128, 0, stream>>>(KFB, KNRM);

    // 4) Q projection (raw q -> BUFB; l2norm fused into attn)
    gemm256<0><<<dim3(128 * 2), 512, 0, stream>>>(XB, WQT, bq, BUFB, nullptr, MROWS, 512, 512,
                                                  nullptr, nullptr, nullptr, nullptr, nullptr,
                                                  128, 2);

    // 5) fused attention (q-norm + allpad inside) -> aligned (BUFC), bypass
    attn_kernel<<<dim3(NTOK / 16, BATCH), 256, 0, stream>>>(BUFB, KNRM, VT, PADM, lsc,
                                                            BUFC, BYP);

    // 6) Wo projection + gated residual -> ypre (BUFB)
    gemm256<1><<<dim3(128 * 2), 512, 0, stream>>>(BUFC, WOT, bo, BUFB, nullptr, MROWS, 512, 512,
                                                  XB, GATE, BYP, nullptr, alp, 128, 2);

    // 7) LN2 -> yb (XB)
    ln2_kernel<<<MROWS, 128, 0, stream>>>(BUFB, ln2_g, ln2_b, XB);

    // 8) MLP (HBUF reuses the VT region — VT is dead by now)
    gemm256<2><<<dim3(128 * 8), 512, 0, stream>>>(XB, W1T, b1, HBUF, nullptr, MROWS, HID, 512,
                                                  nullptr, nullptr, nullptr, nullptr, nullptr,
                                                  128, 8);
    gemm256<3><<<dim3(128 * 2), 512, 0, stream>>>(HBUF, W2T, b2, nullptr, out, MROWS, 512, HID,
                                                  nullptr, nullptr, nullptr, XB, nullptr,
                                                  128, 2);
}

// Round 16
// 357.251 us; speedup vs baseline: 6.0551x; 1.0180x over previous
//
#include <hip/hip_runtime.h>
#include <stdint.h>

// ---------------- problem constants ----------------
#define BATCH 8
#define NTOK 4096          // 64*64
#define CDIM 512
#define TTXT 77
#define TPAD 80
#define NHEAD 8
#define HDIM 64
#define HID 2048           // 4*C
#define MROWS 32768        // B*NTOK
#define NEGINF (-1e30f)

typedef __attribute__((ext_vector_type(8))) short short8;
typedef __attribute__((ext_vector_type(4))) float f32x4;

__device__ __forceinline__ float b2f(unsigned short u) {
    union { unsigned int i; float f; } x; x.i = ((unsigned int)u) << 16; return x.f;
}
__device__ __forceinline__ unsigned short f2b(float f) {
    union { float f; unsigned int i; } x; x.f = f;
    unsigned int i = x.i;
    return (unsigned short)((i + 0x7fffu + ((i >> 16) & 1u)) >> 16);
}

// async global->LDS, 16B per lane; LDS dest must be linear in lane order
__device__ __forceinline__ void gload16(const void* g, void* l) {
    __builtin_amdgcn_global_load_lds(
        (const __attribute__((address_space(1))) unsigned int*)g,
        (__attribute__((address_space(3))) unsigned int*)l, 16, 0, 0);
}

// ---------------- workspace layout (bytes) ----------------
#define OFF_WQT   ((size_t)0)
#define OFF_WKT   (OFF_WQT + 512*512*2)
#define OFF_WVT   (OFF_WKT + 512*512*2)
#define OFF_WOT   (OFF_WVT + 512*512*2)
#define OFF_W1T   (OFF_WOT + 512*512*2)
#define OFF_W2T   (OFF_W1T + (size_t)2048*512*2)
#define OFF_TEXTB (OFF_W2T + (size_t)512*2048*2)
#define OFF_KFB   (OFF_TEXTB + (size_t)640*512*2)
#define OFF_KNRM  (OFF_KFB + (size_t)640*512*2)
#define OFF_VPAD  (OFF_KNRM + (size_t)640*512*2)
#define OFF_PADM  (OFF_VPAD + (size_t)640*512*2)
#define OFF_ALLP  (OFF_PADM + 2560)
#define OFF_GATE  (OFF_ALLP + 256)
#define OFF_BYP   (OFF_GATE + (size_t)MROWS*4)
#define OFF_XB    (OFF_BYP + (size_t)MROWS*4)
#define OFF_BUFB  (OFF_XB + (size_t)MROWS*CDIM*2)
#define OFF_BUFC  (OFF_BUFB + (size_t)MROWS*CDIM*2)
#define OFF_H     (OFF_BUFC + (size_t)MROWS*CDIM*2)
#define WS_NEED   (OFF_H + (size_t)MROWS*HID*2)
// VT overlays HBUF (dead until the MLP phase): [B*NHEAD][64][96] bf16 = 768 KiB
#define OFF_VT    OFF_H

// ---------------- small helpers ----------------
__device__ __forceinline__ float waveReduceAdd(float v) {
#pragma unroll
    for (int m = 1; m < 64; m <<= 1) v += __shfl_xor(v, m);
    return v;
}
__device__ __forceinline__ float red16Max(float v) {
#pragma unroll
    for (int m = 1; m < 16; m <<= 1) v = fmaxf(v, __shfl_xor(v, m));
    return v;
}
__device__ __forceinline__ float red16Add(float v) {
#pragma unroll
    for (int m = 1; m < 16; m <<= 1) v += __shfl_xor(v, m);
    return v;
}
__device__ __forceinline__ float red16Min(float v) {
#pragma unroll
    for (int m = 1; m < 16; m <<= 1) v = fminf(v, __shfl_xor(v, m));
    return v;
}

// ---------------- prep mega-kernel ----------------
// blocks [0,3072): 6 weight transposes fp32 [R][C] -> bf16 [C][R]
// blocks [3072,3712): text rows -> bf16 (padded to 80/batch) + pad mask
// blocks [3712,3728): zero-fill VT pad slots t in [80,96)
__global__ __launch_bounds__(256) void prep_kernel(
    const float* __restrict__ Wq, const float* __restrict__ Wk,
    const float* __restrict__ Wv, const float* __restrict__ Wo,
    const float* __restrict__ W1, const float* __restrict__ W2,
    unsigned short* __restrict__ WQT, unsigned short* __restrict__ WKT,
    unsigned short* __restrict__ WVT, unsigned short* __restrict__ WOT,
    unsigned short* __restrict__ W1T, unsigned short* __restrict__ W2T,
    const float* __restrict__ text, unsigned short* __restrict__ textb,
    float* __restrict__ padm, unsigned short* __restrict__ vt)
{
    __shared__ float tile[32][33];
    __shared__ float sred[4];
    int b = blockIdx.x;
    const int tid = threadIdx.x;

    if (b >= 3712) {
        const int i = b - 3712;
        const int bh = i * 4 + (tid >> 6), d = tid & 63;
        uint4 z = {0u, 0u, 0u, 0u};
        uint4* p = (uint4*)(vt + ((size_t)bh * 64 + d) * 96 + 80);
        p[0] = z; p[1] = z;
        return;
    }
    if (b >= 3072) {
        const int r = b - 3072;                 // 0..639
        const int tb = r / TPAD, t = r % TPAD;
        if (t < TTXT) {
            const float2 v = ((const float2*)(text + ((size_t)(tb * TTXT + t)) * 512))[tid];
            float a = fabsf(v.x) + fabsf(v.y);
            a = waveReduceAdd(a);
            if ((tid & 63) == 0) sred[tid >> 6] = a;
            __syncthreads();
            const float asum = sred[0] + sred[1] + sred[2] + sred[3];
            ushort2 o; o.x = f2b(v.x); o.y = f2b(v.y);
            ((ushort2*)(textb + (size_t)r * 512))[tid] = o;
            if (tid == 0) padm[r] = (asum <= 1e-6f) ? 1.f : 0.f;
        } else {
            ushort2 z; z.x = 0; z.y = 0;
            ((ushort2*)(textb + (size_t)r * 512))[tid] = z;
            if (tid == 0) padm[r] = 1.f;
        }
        return;
    }

    const float* src; unsigned short* dst; int R, C, cx, ry;
    if (b < 1024)       { src = W1; dst = W1T; R = 512;  C = 2048; cx = b & 63; ry = b >> 6; }
    else if (b < 2048)  { b -= 1024; src = W2; dst = W2T; R = 2048; C = 512; cx = b & 15; ry = b >> 4; }
    else {
        b -= 2048; const int which = b >> 8; b &= 255;
        R = 512; C = 512; cx = b & 15; ry = b >> 4;
        src = (which == 0) ? Wq : (which == 1) ? Wk : (which == 2) ? Wv : Wo;
        dst = (which == 0) ? WQT : (which == 1) ? WKT : (which == 2) ? WVT : WOT;
    }
    const int tx = threadIdx.x & 31, ty = threadIdx.x >> 5;  // ty 0..7
    const int c0 = cx * 32, r0 = ry * 32;
#pragma unroll
    for (int i = 0; i < 32; i += 8)
        tile[ty + i][tx] = src[(size_t)(r0 + ty + i) * C + c0 + tx];
    __syncthreads();
#pragma unroll
    for (int i = 0; i < 32; i += 8)
        dst[(size_t)(c0 + ty + i) * R + r0 + tx] = f2b(tile[tx][ty + i]);
}

// ---------------- LN1 + gate ----------------
__global__ __launch_bounds__(128) void ln1_gate_kernel(
    const float* __restrict__ vin, const float* __restrict__ g1, const float* __restrict__ b1v,
    const float* __restrict__ Wg, const float* __restrict__ bg,
    unsigned short* __restrict__ xb, float* __restrict__ gate)
{
    __shared__ float sred[4];
    const int row = blockIdx.x, tid = threadIdx.x;
    const float4 v = *(const float4*)(vin + (size_t)row * 512 + tid * 4);
    float s = v.x + v.y + v.z + v.w;
    float s2 = v.x * v.x + v.y * v.y + v.z * v.z + v.w * v.w;
    s = waveReduceAdd(s); s2 = waveReduceAdd(s2);
    if ((tid & 63) == 0) { sred[tid >> 6] = s; sred[2 + (tid >> 6)] = s2; }
    __syncthreads();
    s = sred[0] + sred[1]; s2 = sred[2] + sred[3];
    const float mu = s * (1.f / 512.f);
    float var = s2 * (1.f / 512.f) - mu * mu;
    const float rs = rsqrtf(fmaxf(var, 0.f) + 1e-5f);
    const float4 gg = *(const float4*)(g1 + tid * 4);
    const float4 bb = *(const float4*)(b1v + tid * 4);
    const float x0 = (v.x - mu) * rs * gg.x + bb.x;
    const float x1 = (v.y - mu) * rs * gg.y + bb.y;
    const float x2 = (v.z - mu) * rs * gg.z + bb.z;
    const float x3 = (v.w - mu) * rs * gg.w + bb.w;
    ushort4 o; o.x = f2b(x0); o.y = f2b(x1); o.z = f2b(x2); o.w = f2b(x3);
    *(ushort4*)(xb + (size_t)row * 512 + tid * 4) = o;
    const float4 wg = *(const float4*)(Wg + tid * 4);
    float gp = x0 * wg.x + x1 * wg.y + x2 * wg.z + x3 * wg.w;
    gp = waveReduceAdd(gp);
    __syncthreads();
    if ((tid & 63) == 0) sred[tid >> 6] = gp;
    __syncthreads();
    if (tid == 0) {
        float z = sred[0] + sred[1] + bg[0];
        gate[row] = 1.f / (1.f + __expf(-z));
    }
}

// ---------------- LN2 ----------------
__global__ __launch_bounds__(128) void ln2_kernel(
    const unsigned short* __restrict__ yin, const float* __restrict__ g2, const float* __restrict__ b2v,
    unsigned short* __restrict__ yb)
{
    __shared__ float sred[4];
    const int row = blockIdx.x, tid = threadIdx.x;
    ushort4 u = *(const ushort4*)(yin + (size_t)row * 512 + tid * 4);
    float v0 = b2f(u.x), v1 = b2f(u.y), v2 = b2f(u.z), v3 = b2f(u.w);
    float s = v0 + v1 + v2 + v3;
    float s2 = v0 * v0 + v1 * v1 + v2 * v2 + v3 * v3;
    s = waveReduceAdd(s); s2 = waveReduceAdd(s2);
    if ((tid & 63) == 0) { sred[tid >> 6] = s; sred[2 + (tid >> 6)] = s2; }
    __syncthreads();
    s = sred[0] + sred[1]; s2 = sred[2] + sred[3];
    const float mu = s * (1.f / 512.f);
    float var = s2 * (1.f / 512.f) - mu * mu;
    const float rs = rsqrtf(fmaxf(var, 0.f) + 1e-5f);
    const float4 gg = *(const float4*)(g2 + tid * 4);
    const float4 bb = *(const float4*)(b2v + tid * 4);
    ushort4 o;
    o.x = f2b((v0 - mu) * rs * gg.x + bb.x);
    o.y = f2b((v1 - mu) * rs * gg.y + bb.y);
    o.z = f2b((v2 - mu) * rs * gg.z + bb.z);
    o.w = f2b((v3 - mu) * rs * gg.w + bb.w);
    *(ushort4*)(yb + (size_t)row * 512 + tid * 4) = o;
}

// ---------------- row l2-normalize bf16 -> bf16 (K only, 640 rows) ----------------
__global__ __launch_bounds__(128) void l2norm_kernel(
    const unsigned short* __restrict__ in, unsigned short* __restrict__ out)
{
    __shared__ float sred[2];
    const int row = blockIdx.x, tid = threadIdx.x;
    ushort4 u = *(const ushort4*)(in + (size_t)row * 512 + tid * 4);
    float v0 = b2f(u.x), v1 = b2f(u.y), v2 = b2f(u.z), v3 = b2f(u.w);
    float ss = v0 * v0 + v1 * v1 + v2 * v2 + v3 * v3;
    ss = waveReduceAdd(ss);
    if ((tid & 63) == 0) sred[tid >> 6] = ss;
    __syncthreads();
    ss = sred[0] + sred[1];
    const float inv = 1.f / fmaxf(sqrtf(ss), 1e-6f);
    ushort4 o;
    o.x = f2b(v0 * inv); o.y = f2b(v1 * inv); o.z = f2b(v2 * inv); o.w = f2b(v3 * inv);
    *(ushort4*)(out + (size_t)row * 512 + tid * 4) = o;
}

// ---------------- merged text K/V GEMM (128x128, M=640) ----------------
// grid (5,4,2): z=0 -> KFB (row-major bf16); z=1 -> VT direct (per-head transposed)
__global__ __launch_bounds__(256) void gemm_kv(
    const unsigned short* __restrict__ A,
    const unsigned short* __restrict__ BtK, const unsigned short* __restrict__ BtV,
    const float* __restrict__ bk, const float* __restrict__ bv,
    unsigned short* __restrict__ kfb, unsigned short* __restrict__ vt)
{
    const int K = 512, N = 512;
    const unsigned short* Bt = blockIdx.z ? BtV : BtK;
    const float* bias = blockIdx.z ? bv : bk;
    __shared__ unsigned short sA[128 * 64];
    __shared__ unsigned short sB[128 * 64];
    char* cA = (char*)sA;
    char* cB = (char*)sB;
    const int tid = threadIdx.x;
    const int lane = tid & 63, w = tid >> 6;
    const int g = lane >> 4, ln = lane & 15;
    const int WR = w >> 1, WC = w & 1;
    const int rowA0 = blockIdx.x * 128, colB0 = blockIdx.y * 128;

    f32x4 acc[4][4];
#pragma unroll
    for (int m = 0; m < 4; ++m)
#pragma unroll
        for (int n = 0; n < 4; ++n) acc[m][n] = (f32x4){0.f, 0.f, 0.f, 0.f};

    for (int k0 = 0; k0 < K; k0 += 64) {
        __syncthreads();
#pragma unroll
        for (int i = 0; i < 4; ++i) {
            int c = tid + i * 256;
            int row = c >> 3, kc = c & 7;
            int kcs = kc ^ (row & 7);
            gload16(A + (size_t)(rowA0 + row) * K + k0 + kcs * 8, cA + c * 16);
            gload16(Bt + (size_t)(colB0 + row) * K + k0 + kcs * 8, cB + c * 16);
        }
        __syncthreads();
#pragma unroll
        for (int kk = 0; kk < 2; ++kk) {
            short8 af[4], bf[4];
#pragma unroll
            for (int m = 0; m < 4; ++m) {
                int row = WR * 64 + m * 16 + ln;
                af[m] = *(const short8*)(cA + row * 128 + ((kk * 64 + g * 16) ^ ((row & 7) << 4)));
            }
#pragma unroll
            for (int n = 0; n < 4; ++n) {
                int col = WC * 64 + n * 16 + ln;
                bf[n] = *(const short8*)(cB + col * 128 + ((kk * 64 + g * 16) ^ ((col & 7) << 4)));
            }
#pragma unroll
            for (int m = 0; m < 4; ++m)
#pragma unroll
                for (int n = 0; n < 4; ++n)
                    acc[m][n] = __builtin_amdgcn_mfma_f32_16x16x32_bf16(af[m], bf[n], acc[m][n], 0, 0, 0);
        }
    }

#pragma unroll
    for (int m = 0; m < 4; ++m) {
        const int rbase = rowA0 + WR * 64 + m * 16 + g * 4;
#pragma unroll
        for (int n = 0; n < 4; ++n) {
            const int col = colB0 + WC * 64 + n * 16 + ln;
            const float bcol = bias[col];
#pragma unroll
            for (int i = 0; i < 4; ++i) {
                const int row = rbase + i;
                const float v = acc[m][n][i] + bcol;
                if (blockIdx.z == 0) {
                    kfb[(size_t)row * N + col] = f2b(v);
                } else {
                    const int tb = row / TPAD, t = row - tb * TPAD;
                    const int h = col >> 6, d = col & 63;
                    vt[((size_t)(tb * NHEAD + h) * 64 + d) * 96 + t] = f2b(v);
                }
            }
        }
    }
}

// ---------------- 256x256 bf16 MFMA GEMM, R10 schedule + COMPILE-TIME K ----------------
// Identical schedule to the reproduced-best R10/R15 build; K, N-of-output and grid
// params are now template constants so all address math strength-reduces (falsifies
// the "hidden VALU issue pressure" theory behind VALUBusy=60%).
#define SEAM() __builtin_amdgcn_sched_barrier(0x106)

template<int EPI, int K, int NOUT, int GXM, int GYN>
__global__ __launch_bounds__(512, 2) void gemm256(
    const unsigned short* __restrict__ A, const unsigned short* __restrict__ Bt,
    const float* __restrict__ bias,
    unsigned short* __restrict__ outb, float* __restrict__ outf,
    const unsigned short* __restrict__ xres, const float* __restrict__ gate,
    const float* __restrict__ byp, const unsigned short* __restrict__ yres,
    const float* __restrict__ alphaPtr)
{
    __shared__ unsigned short lds[2][2][16384];   // [buf][A/B][256*64] = 128 KiB
    const int tid = threadIdx.x;
    const int lane = tid & 63, w = tid >> 6;
    const int g = lane >> 4, ln = lane & 15;
    const int wr = w >> 2, wc = w & 3;

    // XCD-chunked bijective swizzle (GXM multiple of 8)
    int bm, bn;
    {
        const int L = (int)blockIdx.x;
        const int xcd = L & 7, j = L >> 3;
        const int rl = j / GYN;
        bn = j - rl * GYN;
        bm = xcd * (GXM >> 3) + rl;
    }
    const int rowA0 = bm * 256, colB0 = bn * 256;
    constexpr int nt = K >> 6;

    auto stageA = [&](int t, int mh) {
        const int buf = t & 1;
#pragma unroll
        for (int r = 0; r < 2; ++r) {
            const int c = tid + r * 512;
            const int prl = c >> 3, kc = c & 7;
            const int grow = rowA0 + ((prl >> 6) << 7) + (mh << 6) + (prl & 63);
            gload16(A + (size_t)grow * K + (t << 6) + ((kc ^ (prl & 7)) << 3),
                    (char*)&lds[buf][0][mh * 8192] + c * 16);
        }
    };
    auto stageB = [&](int t, int nh) {
        const int buf = t & 1;
#pragma unroll
        for (int r = 0; r < 2; ++r) {
            const int c = tid + r * 512;
            const int prl = c >> 3, kc = c & 7;
            const int gcol = colB0 + ((prl >> 5) << 6) + (nh << 5) + (prl & 31);
            gload16(Bt + (size_t)gcol * K + (t << 6) + ((kc ^ (prl & 7)) << 3),
                    (char*)&lds[buf][1][nh * 8192] + c * 16);
        }
    };

    f32x4 acc[8][4];
#pragma unroll
    for (int m = 0; m < 8; ++m)
#pragma unroll
        for (int n = 0; n < 4; ++n) acc[m][n] = (f32x4){0.f, 0.f, 0.f, 0.f};

    // prologue: stage tile 0 fully; drain; barrier  (fill = 1 tile)
    stageA(0, 0); stageA(0, 1); stageB(0, 0); stageB(0, 1);
    asm volatile("s_waitcnt vmcnt(0)" ::: "memory");
    __builtin_amdgcn_s_barrier();

    const int sw  = (ln & 7) << 4;
    const int kb0 = (g * 16) ^ sw;
    const int kb1 = (64 + g * 16) ^ sw;
    const int arow = (wr * 64 + ln) * 128;
    const int brow = (wc * 32 + ln) * 128;

    short8 afr[4][2], bfr[4][2];

#pragma unroll 2
    for (int t = 0; t < nt; ++t) {
        const char* lA = (const char*)&lds[t & 1][0][0];
        const char* lB = (const char*)&lds[t & 1][1][0];
        const bool pf = (t + 1 < nt);

        // ---- q0: (m0-3, n0-1), 12 ds_reads; stage A(t+1) both halves ----
#pragma unroll
        for (int m = 0; m < 4; ++m) {
            afr[m][0] = *(const short8*)(lA + arow + m * 2048 + kb0);
            afr[m][1] = *(const short8*)(lA + arow + m * 2048 + kb1);
        }
#pragma unroll
        for (int n = 0; n < 2; ++n) {
            bfr[n][0] = *(const short8*)(lB + brow + n * 2048 + kb0);
            bfr[n][1] = *(const short8*)(lB + brow + n * 2048 + kb1);
        }
        if (pf) { stageA(t + 1, 0); stageA(t + 1, 1); }
        __builtin_amdgcn_s_setprio(1);
#pragma unroll
        for (int m = 0; m < 4; ++m)
#pragma unroll
            for (int n = 0; n < 2; ++n) {
                acc[m][n] = __builtin_amdgcn_mfma_f32_16x16x32_bf16(afr[m][0], bfr[n][0], acc[m][n], 0, 0, 0);
                acc[m][n] = __builtin_amdgcn_mfma_f32_16x16x32_bf16(afr[m][1], bfr[n][1], acc[m][n], 0, 0, 0);
            }
        __builtin_amdgcn_s_setprio(0);
        SEAM();

        // ---- q1: (m0-3, n2-3), 4 ds_reads; stage B(t+1) both halves ----
#pragma unroll
        for (int n = 2; n < 4; ++n) {
            bfr[n][0] = *(const short8*)(lB + brow + (n & 1) * 2048 + 16384 + kb0);
            bfr[n][1] = *(const short8*)(lB + brow + (n & 1) * 2048 + 16384 + kb1);
        }
        if (pf) { stageB(t + 1, 0); stageB(t + 1, 1); }
        __builtin_amdgcn_s_setprio(1);
#pragma unroll
        for (int m = 0; m < 4; ++m)
#pragma unroll
            for (int n = 2; n < 4; ++n) {
                acc[m][n] = __builtin_amdgcn_mfma_f32_16x16x32_bf16(afr[m][0], bfr[n][0], acc[m][n], 0, 0, 0);
                acc[m][n] = __builtin_amdgcn_mfma_f32_16x16x32_bf16(afr[m][1], bfr[n][1], acc[m][n], 0, 0, 0);
            }
        __builtin_amdgcn_s_setprio(0);
        SEAM();

        // ---- q2: (m4-7, n0-1), 8 ds_reads ----
#pragma unroll
        for (int m = 0; m < 4; ++m) {
            afr[m][0] = *(const short8*)(lA + arow + m * 2048 + 16384 + kb0);
            afr[m][1] = *(const short8*)(lA + arow + m * 2048 + 16384 + kb1);
        }
        __builtin_amdgcn_s_setprio(1);
#pragma unroll
        for (int m = 0; m < 4; ++m)
#pragma unroll
            for (int n = 0; n < 2; ++n) {
                acc[m + 4][n] = __builtin_amdgcn_mfma_f32_16x16x32_bf16(afr[m][0], bfr[n][0], acc[m + 4][n], 0, 0, 0);
                acc[m + 4][n] = __builtin_amdgcn_mfma_f32_16x16x32_bf16(afr[m][1], bfr[n][1], acc[m + 4][n], 0, 0, 0);
            }
        __builtin_amdgcn_s_setprio(0);
        SEAM();

        // ---- q3: (m4-7, n2-3), 0 ds_reads ----
        __builtin_amdgcn_s_setprio(1);
#pragma unroll
        for (int m = 0; m < 4; ++m)
#pragma unroll
            for (int n = 2; n < 4; ++n) {
                acc[m + 4][n] = __builtin_amdgcn_mfma_f32_16x16x32_bf16(afr[m][0], bfr[n][0], acc[m + 4][n], 0, 0, 0);
                acc[m + 4][n] = __builtin_amdgcn_mfma_f32_16x16x32_bf16(afr[m][1], bfr[n][1], acc[m + 4][n], 0, 0, 0);
            }
        __builtin_amdgcn_s_setprio(0);

        // ---- tile boundary: t+1 fully landed; all waves past tile-t reads ----
        if (pf) {
            asm volatile("s_waitcnt vmcnt(0)" ::: "memory");
            __builtin_amdgcn_s_barrier();
        }
    }

    // ---- epilogue ----
    const float alpha = (EPI == 1) ? *alphaPtr : 0.f;
#pragma unroll
    for (int m = 0; m < 8; ++m) {
        const int rbase = rowA0 + wr * 128 + m * 16 + g * 4;
#pragma unroll
        for (int n = 0; n < 4; ++n) {
            const int col = colB0 + wc * 64 + n * 16 + ln;
            const float bcol = bias[col];
#pragma unroll
            for (int i = 0; i < 4; ++i) {
                const int row = rbase + i;
                const float v = acc[m][n][i] + bcol;
                if (EPI == 0) {
                    outb[(size_t)row * NOUT + col] = f2b(v);
                } else if (EPI == 1) {
                    float yp = b2f(xres[(size_t)row * NOUT + col]) + alpha * gate[row] * byp[row] * v;
                    outb[(size_t)row * NOUT + col] = f2b(yp);
                } else if (EPI == 2) {
                    const float u2 = 2.f * v * (0.7978845608f + 0.0356774081f * v * v);
                    const float tt = 1.f - 2.f / (__expf(u2) + 1.f);
                    outb[(size_t)row * NOUT + col] = f2b(0.5f * v * (1.f + tt));
                } else {
                    outf[(size_t)row * NOUT + col] = b2f(yres[(size_t)row * NOUT + col]) + v;
                }
            }
        }
    }
}
#undef SEAM

// ---------------- fused attention (q-l2norm + allpad fused in) ----------------
// grid: (NTOK/16, B), block 256 = 4 waves; each wave: same 16 rows, heads {w, w+4}.
__global__ __launch_bounds__(256) void attn_kernel(
    const unsigned short* __restrict__ qn,   // [MROWS,512] raw q, bf16
    const unsigned short* __restrict__ kn,   // [B,80,512] l2-normed k, bf16
    const unsigned short* __restrict__ vt,   // [B*8][64][96] per-head V^T, bf16
    const float* __restrict__ padm,          // [B,80] 1.0 = pad
    const float* __restrict__ lscPtr,
    unsigned short* __restrict__ aligned,    // [MROWS,512] bf16
    float* __restrict__ bypass)              // [MROWS]
{
    const int b = blockIdx.y;
    const int n0 = blockIdx.x * 16;
    const int tid = threadIdx.x;
    const int w = tid >> 6, lane = tid & 63, g = lane >> 4, ln = lane & 15;
    __shared__ unsigned short s_p[4][16][104];
    __shared__ float s_conf[4][16];
    __shared__ float s_inv[16];

    // pad-mask of this lane's 5 t-columns (depends only on ln)
    float pm[5];
#pragma unroll
    for (int tt = 0; tt < 5; ++tt) {
        int t = ln + tt * 16;
        pm[tt] = (t < TTXT) ? padm[b * TPAD + t] : 1.f;
    }
    // all-pad check (fused allpad): min over t<77 of padm
    {
        float pmn = fminf(fminf(pm[0], pm[1]), fminf(fminf(pm[2], pm[3]), pm[4]));
        pmn = red16Min(pmn);
        if (pmn > 0.5f) {
            uint4 z = {0u, 0u, 0u, 0u};
#pragma unroll
            for (int j = 0; j < 4; ++j) {
                int id = tid + j * 256;
                int row = id >> 6, c8 = id & 63;
                *(uint4*)(aligned + ((size_t)(b * NTOK + n0 + row)) * 512 + c8 * 8) = z;
            }
            if (tid < 16) bypass[b * NTOK + n0 + tid] = 0.f;
            return;
        }
    }

    // ---- q-norm preamble: 16 rows x 512 ch; thread (r=tid>>4, seg=tid&15) ----
    {
        const int r = tid >> 4, seg = tid & 15;
        const unsigned short* qp = qn + ((size_t)(b * NTOK + n0 + r)) * 512 + seg * 32;
        float ss = 0.f;
#pragma unroll
        for (int j = 0; j < 4; ++j) {
            short8 u = *(const short8*)(qp + j * 8);
#pragma unroll
            for (int e = 0; e < 8; ++e) {
                float f = b2f(((const unsigned short*)&u)[e]);
                ss += f * f;
            }
        }
        ss = red16Add(ss);
        if (seg == 0) s_inv[r] = 1.f / fmaxf(sqrtf(ss), 1e-6f);
    }

    float lscale;
    {
        float ls = *lscPtr;
        ls = fminf(fmaxf(ls, -2.f), 2.f);
        lscale = __expf(ls) * 0.125f;
    }

    for (int j = g; j < 24; j += 4) s_p[w][ln][80 + j] = 0;
    __syncthreads();                               // s_inv ready

    float conf_acc[4] = {0.f, 0.f, 0.f, 0.f};
    const size_t qrow = ((size_t)(b * NTOK + n0 + ln)) * 512;

#pragma unroll
    for (int hh = 0; hh < 2; ++hh) {
        const int h = w + hh * 4;
        short8 a0 = *(const short8*)(qn + qrow + h * 64 + g * 8);
        short8 a1 = *(const short8*)(qn + qrow + h * 64 + 32 + g * 8);
        f32x4 sim[5];
#pragma unroll
        for (int tt = 0; tt < 5; ++tt) {
            const size_t kbase = ((size_t)(b * TPAD + tt * 16 + ln)) * 512 + h * 64;
            short8 b0 = *(const short8*)(kn + kbase + g * 8);
            short8 b1 = *(const short8*)(kn + kbase + 32 + g * 8);
            f32x4 c = (f32x4){0.f, 0.f, 0.f, 0.f};
            c = __builtin_amdgcn_mfma_f32_16x16x32_bf16(a0, b0, c, 0, 0, 0);
            c = __builtin_amdgcn_mfma_f32_16x16x32_bf16(a1, b1, c, 0, 0, 0);
            sim[tt] = c;
        }
#pragma unroll
        for (int i = 0; i < 4; ++i) {
            const float qs = lscale * s_inv[g * 4 + i];   // row = g*4+i (C/D layout)
            float v[5];
#pragma unroll
            for (int tt = 0; tt < 5; ++tt)
                v[tt] = (pm[tt] == 0.f) ? sim[tt][i] * qs : NEGINF;

            float lm = v[0];
#pragma unroll
            for (int tt = 1; tt < 5; ++tt) lm = fmaxf(lm, v[tt]);
            const float m1 = red16Max(lm);
            float lm2 = -3.0e38f;
#pragma unroll
            for (int tt = 0; tt < 5; ++tt) if (v[tt] < m1) lm2 = fmaxf(lm2, v[tt]);
            const float m2 = red16Max(lm2);
            float lm3 = -3.0e38f;
#pragma unroll
            for (int tt = 0; tt < 5; ++tt) if (v[tt] < m2) lm3 = fmaxf(lm3, v[tt]);
            const float m3 = red16Max(lm3);
            // packed count reduction: c1 + 128*c2 (both <= 80 < 128)
            float lc = 0.f;
#pragma unroll
            for (int tt = 0; tt < 5; ++tt) {
                if (v[tt] >= m1) lc += 1.f;
                if (v[tt] >= m2) lc += 128.f;
            }
            const float cpk = red16Add(lc);
            const float c2 = floorf(cpk * (1.f / 128.f));
            const float c1 = cpk - 128.f * c2;
            const float th = (c1 >= 3.f) ? m1 : ((c2 >= 3.f) ? m2 : m3);

            float p[5], lsum = 0.f, lcnt = 0.f;
#pragma unroll
            for (int tt = 0; tt < 5; ++tt) {
                float pv = (v[tt] >= th) ? __expf(v[tt] - m1) : 0.f;
                p[tt] = pv;
                lsum += pv;
                lcnt += (pv > 0.f) ? 1.f : 0.f;
            }
            const float psum = red16Add(lsum);
            const float pcnt = red16Add(lcnt);
            const float inv = 1.f / fmaxf(psum, 1e-20f);

            float lmaxp = 0.f, lent = 0.f;
#pragma unroll
            for (int tt = 0; tt < 5; ++tt) {
                float a = p[tt] * inv;
                p[tt] = a;
                lmaxp = fmaxf(lmaxp, a);
                if (a > 0.f) {
                    float pp = fmaxf(a, 1e-8f);
                    lent += -pp * __logf(pp);
                }
            }
            const float maxp = red16Max(lmaxp);
            float ent = red16Add(lent);
            ent += (77.f - pcnt) * 1.8420680744e-7f;
            const float teff = fmaxf(pcnt, 2.f);
            const float entropy = fmaxf(ent / __logf(teff), 0.f);
            const float confh = fminf(fmaxf(maxp * (1.f - entropy), 0.f), 1.f);
            conf_acc[i] += confh;

#pragma unroll
            for (int tt = 0; tt < 5; ++tt)
                s_p[w][g * 4 + i][ln + tt * 16] = f2b(p[tt]);
        }
        short8 af[3];
#pragma unroll
        for (int k = 0; k < 3; ++k)
            af[k] = *(const short8*)(&s_p[w][ln][k * 32 + g * 8]);
        const size_t vtb = ((size_t)(b * NHEAD + h)) * 64;
#pragma unroll
        for (int n = 0; n < 4; ++n) {
            f32x4 o = (f32x4){0.f, 0.f, 0.f, 0.f};
#pragma unroll
            for (int k = 0; k < 3; ++k) {
                short8 bf = *(const short8*)(vt + (vtb + n * 16 + ln) * 96 + k * 32 + g * 8);
                o = __builtin_amdgcn_mfma_f32_16x16x32_bf16(af[k], bf, o, 0, 0, 0);
            }
#pragma unroll
            for (int i = 0; i < 4; ++i)
                aligned[((size_t)(b * NTOK + n0 + g * 4 + i)) * 512 + h * 64 + n * 16 + ln] =
                    f2b(o[i]);
        }
    }

    if (ln == 0) {
#pragma unroll
        for (int i = 0; i < 4; ++i) s_conf[w][g * 4 + i] = conf_acc[i];
    }
    __syncthreads();
    if (tid < 16) {
        float c = (s_conf[0][tid] + s_conf[1][tid] + s_conf[2][tid] + s_conf[3][tid]) * 0.125f;
        bypass[b * NTOK + n0 + tid] = (c >= 0.35f) ? 1.f : 0.f;
    }
}

// ---------------- host side ----------------
extern "C" void kernel_launch(void* const* d_in, const int* in_sizes, int n_in,
                              void* d_out, int out_size, void* d_ws, size_t ws_size,
                              hipStream_t stream)
{
    (void)in_sizes; (void)n_in; (void)out_size;
    if (ws_size < WS_NEED) return;

    const float* visual = (const float*)d_in[0];
    const float* text   = (const float*)d_in[1];
    const float* ln1_g  = (const float*)d_in[2];
    const float* ln1_b  = (const float*)d_in[3];
    const float* ln2_g  = (const float*)d_in[4];
    const float* ln2_b  = (const float*)d_in[5];
    const float* Wq = (const float*)d_in[6];   const float* bq = (const float*)d_in[7];
    const float* Wk = (const float*)d_in[8];   const float* bk = (const float*)d_in[9];
    const float* Wv = (const float*)d_in[10];  const float* bv = (const float*)d_in[11];
    const float* Wo = (const float*)d_in[12];  const float* bo = (const float*)d_in[13];
    const float* Wg = (const float*)d_in[14];  const float* bg = (const float*)d_in[15];
    const float* W1 = (const float*)d_in[16];  const float* b1 = (const float*)d_in[17];
    const float* W2 = (const float*)d_in[18];  const float* b2 = (const float*)d_in[19];
    const float* lsc = (const float*)d_in[20];
    const float* alp = (const float*)d_in[21];

    char* ws = (char*)d_ws;
    unsigned short* WQT  = (unsigned short*)(ws + OFF_WQT);
    unsigned short* WKT  = (unsigned short*)(ws + OFF_WKT);
    unsigned short* WVT  = (unsigned short*)(ws + OFF_WVT);
    unsigned short* WOT  = (unsigned short*)(ws + OFF_WOT);
    unsigned short* W1T  = (unsigned short*)(ws + OFF_W1T);
    unsigned short* W2T  = (unsigned short*)(ws + OFF_W2T);
    unsigned short* TEXTB = (unsigned short*)(ws + OFF_TEXTB);
    unsigned short* KFB  = (unsigned short*)(ws + OFF_KFB);
    unsigned short* KNRM = (unsigned short*)(ws + OFF_KNRM);
    float* PADM = (float*)(ws + OFF_PADM);
    float* GATE = (float*)(ws + OFF_GATE);
    float* BYP  = (float*)(ws + OFF_BYP);
    unsigned short* XB   = (unsigned short*)(ws + OFF_XB);
    unsigned short* BUFB = (unsigned short*)(ws + OFF_BUFB);
    unsigned short* BUFC = (unsigned short*)(ws + OFF_BUFC);
    unsigned short* HBUF = (unsigned short*)(ws + OFF_H);
    unsigned short* VT   = (unsigned short*)(ws + OFF_VT);   // overlays HBUF
    float* out = (float*)d_out;

    // 1) prep: all weight transposes + text bf16/padmask + VT pad zero-fill
    prep_kernel<<<3728, 256, 0, stream>>>(Wq, Wk, Wv, Wo, W1, W2,
                                          WQT, WKT, WVT, WOT, W1T, W2T,
                                          text, TEXTB, PADM, VT);

    // 2) LN1 + gate
    ln1_gate_kernel<<<MROWS, 128, 0, stream>>>(visual, ln1_g, ln1_b, Wg, bg, XB, GATE);

    // 3) text K/V projections in one launch (V writes VT directly) + K l2norm
    gemm_kv<<<dim3(5, 4, 2), 256, 0, stream>>>(TEXTB, WKT, WVT, bk, bv, KFB, VT);
    l2norm_kernel<<<640, 128, 0, stream>>>(KFB, KNRM);

    // 4) Q projection (raw q -> BUFB; l2norm fused into attn)  [K=512, N=512]
    gemm256<0, 512, 512, 128, 2><<<dim3(128 * 2), 512, 0, stream>>>(
        XB, WQT, bq, BUFB, nullptr, nullptr, nullptr, nullptr, nullptr, nullptr);

    // 5) fused attention (q-norm + allpad inside) -> aligned (BUFC), bypass
    attn_kernel<<<dim3(NTOK / 16, BATCH), 256, 0, stream>>>(BUFB, KNRM, VT, PADM, lsc,
                                                            BUFC, BYP);

    // 6) Wo projection + gated residual -> ypre (BUFB)  [K=512, N=512]
    gemm256<1, 512, 512, 128, 2><<<dim3(128 * 2), 512, 0, stream>>>(
        BUFC, WOT, bo, BUFB, nullptr, XB, GATE, BYP, nullptr, alp);

    // 7) LN2 -> yb (XB)
    ln2_kernel<<<MROWS, 128, 0, stream>>>(BUFB, ln2_g, ln2_b, XB);

    // 8) MLP (HBUF reuses the VT region — VT is dead by now)
    gemm256<2, 512, 2048, 128, 8><<<dim3(128 * 8), 512, 0, stream>>>(
        XB, W1T, b1, HBUF, nullptr, nullptr, nullptr, nullptr, nullptr, nullptr);
    gemm256<3, 2048, 512, 128, 2><<<dim3(128 * 2), 512, 0, stream>>>(
        HBUF, W2T, b2, nullptr, out, nullptr, nullptr, nullptr, XB, nullptr);
}